// Round 15
// baseline (50.728 us; speedup 1.0000x reference)
//
#include <hip/hip_runtime.h>
#include <math.h>

#define NPOS 1024   // H*W
#define DH   32     // dim head
#define NBH  8      // B * HEADS
#define CH   256
#define INNER 128   // HEADS*DIM_HEAD

typedef __attribute__((ext_vector_type(4))) _Float16 half4;
typedef __attribute__((ext_vector_type(4))) float f32x4;

// Canonical CDNA 16x16x16 f16 MFMA.  A: row=l&15, k=4*(l>>4)+j.  B: col=l&15,
// same k ordering.  C/D: col=l&15, row=(l>>4)*4+reg.
#define MFMA16(a, b, c) __builtin_amdgcn_mfma_f32_16x16x16f16((a), (b), (c), 0, 0, 0)

union h2u { _Float16 h; unsigned short u; };

__device__ __forceinline__ unsigned short f2h(float f) {
  h2u c; c.h = (_Float16)f; return c.u;
}
__device__ __forceinline__ float h2f(unsigned short u) {
  h2u c; c.u = u; return (float)c.h;
}
__device__ __forceinline__ half4 ldh4(const unsigned short* __restrict__ p) {
  union { half4 v; uint2 u; } r;
  r.u = *(const uint2*)p;
  return r.v;
}

// ---------------------------------------------------------------------------
// Kernel A: fused QKV projection + split-f16 encode.
// 8-wave WG, 1024 WGs: 4 i-singles x 2 c-halves -> 3 scalar streams/wave
// (short lgkmcnt batches) and 4 WG/CU = 100% occupancy to hide s_load
// latency.  Weights via wave-uniform s_loads; x per-lane coalesced VMEM.
// kh=1 waves dump partials to LDS; kh=0 combine + encode.
// Qhi/Qlo/Khi/Klo: [bh][n][d]; Vthi/Vtlo: [bh][d][n].
// ---------------------------------------------------------------------------
__global__ __launch_bounds__(512) void proj_kernel(
    const float* __restrict__ x, const float* __restrict__ Wq,
    const float* __restrict__ Wk, const float* __restrict__ Wv,
    unsigned short* __restrict__ Qhi, unsigned short* __restrict__ Qlo,
    unsigned short* __restrict__ Khi, unsigned short* __restrict__ Klo,
    unsigned short* __restrict__ Vthi, unsigned short* __restrict__ Vtlo)
{
  __shared__ float part[4][3][64];   // [i-group][acc][lane], 3 KB

  const int tid  = threadIdx.x;
  const int lane = tid & 63;
  const int wid  = __builtin_amdgcn_readfirstlane(tid >> 6); // 0..7 SGPR
  const int it   = wid & 3;        // i-group (one i each)
  const int kh   = wid >> 2;       // c-half
  const int n    = blockIdx.x * 64 + lane;  // 0..1023
  const int i0   = blockIdx.y * 4 + it;     // 0..127 (wave-uniform)
  const int b    = blockIdx.z;

  const float* xb = x  + (size_t)b * CH * NPOS + n;
  const float* wq = Wq + (size_t)i0 * CH;
  const float* wk = Wk + (size_t)i0 * CH;
  const float* wv = Wv + (size_t)i0 * CH;

  float aq0 = 0.f, ak0 = 0.f, av0 = 0.f;

  const int cbase = kh * 128;
  #pragma unroll 16
  for (int cc = 0; cc < 128; ++cc) {
    const int c = cbase + cc;
    const float xv = xb[(size_t)c * NPOS];
    aq0 += wq[c] * xv;
    ak0 += wk[c] * xv;
    av0 += wv[c] * xv;
  }

  if (kh == 1) {
    part[it][0][lane] = aq0;
    part[it][1][lane] = ak0;
    part[it][2][lane] = av0;
  }
  __syncthreads();
  if (kh == 1) return;

  aq0 += part[it][0][lane];
  ak0 += part[it][1][lane];
  av0 += part[it][2][lane];

  const float qs = 0.17677669529663687f;  // 1/sqrt(32)
  aq0 *= qs;

  const int h = i0 >> 5, d = i0 & 31, bh = b * 4 + h;

  unsigned short qh0 = f2h(aq0);
  unsigned short ql0 = f2h(aq0 - h2f(qh0));
  unsigned short kh0v = f2h(ak0);
  unsigned short kl0 = f2h(ak0 - h2f(kh0v));
  unsigned short vh0 = f2h(av0);
  unsigned short vl0 = f2h(av0 - h2f(vh0));

  const size_t qk = ((size_t)bh * NPOS + n) * DH + d;
  Qhi[qk] = qh0;
  Qlo[qk] = ql0;
  Khi[qk] = kh0v;
  Klo[qk] = kl0;

  const size_t vt = ((size_t)bh * DH + d) * NPOS + n;
  Vthi[vt] = vh0;
  Vtlo[vt] = vl0;
}

// ---------------------------------------------------------------------------
// Kernel B: fully fused attention (UNCHANGED from passing R9-R13 version).
// S^T = K·Q^T; KAN + exp(kan-Bnd) in-register; f16 P = B-operand fragment
// for O^T = V^T·P^T; denominator sums same f16-rounded p; 8-way LDS combine.
// ---------------------------------------------------------------------------
__global__ __launch_bounds__(512) void attn_fused(
    const unsigned short* __restrict__ Qhi, const unsigned short* __restrict__ Qlo,
    const unsigned short* __restrict__ Khi, const unsigned short* __restrict__ Klo,
    const unsigned short* __restrict__ Vthi, const unsigned short* __restrict__ Vtlo,
    const float* __restrict__ bwp, const float* __restrict__ swp,
    const float* __restrict__ ssp, float* __restrict__ Onorm)
{
  __shared__ float DlO[8][32][17];
  __shared__ float DlS[8][4][17];

  const int tid = threadIdx.x;
  const int l   = tid & 63;
  const int w   = tid >> 6;        // 0..7
  const int lr  = l & 15;
  const int lg  = l >> 4;          // 0..3
  const int ko  = lg * 4;
  const int bh  = blockIdx.x;      // 0..7 (== XCD)
  const int q0  = blockIdx.y * 16;

  // ---- uniform KAN constants ----
  const float sc = ssp[0];
  const float bw = bwp[0];
  float C[8];
  #pragma unroll
  for (int j = 0; j < 8; ++j) C[j] = swp[j] * sc;
  float maxc = 0.f;
  #pragma unroll
  for (int j = 0; j < 8; ++j) maxc = fmaxf(maxc, fabsf(C[j]));
  const float Bnd = fabsf(bw) * 6.0f + maxc;    // >= max_x kan(x)

  float A0[5], A1[5], A2[5], A3[5];             // per-cell cubic; -Bnd in A0
  #pragma unroll
  for (int c = 0; c < 5; ++c) {
    A0[c] = (C[c] + 4.f * C[c+1] + C[c+2]) * (1.f / 6.f) - Bnd;
    A1[c] = (-3.f * C[c] + 3.f * C[c+2]) * (1.f / 6.f);
    A2[c] = (3.f * C[c] - 6.f * C[c+1] + 3.f * C[c+2]) * (1.f / 6.f);
    A3[c] = (-C[c] + 3.f * C[c+1] - 3.f * C[c+2] + C[c+3]) * (1.f / 6.f);
  }

  // ---- Q fragments (B-operand, persistent): col q = q0+lr, k-dim d ----
  const size_t qb = ((size_t)bh * NPOS + q0 + lr) * DH;
  const half4 Bq_h0 = ldh4(Qhi + qb + ko);
  const half4 Bq_h1 = ldh4(Qhi + qb + 16 + ko);
  const half4 Bq_l0 = ldh4(Qlo + qb + ko);
  const half4 Bq_l1 = ldh4(Qlo + qb + 16 + ko);

  // ---- V^T bases (A-operand): row d = lr (+16), k = key ----
  const unsigned short* vh0 = Vthi + ((size_t)bh * DH + lr) * NPOS;
  const unsigned short* vh1 = vh0 + (size_t)16 * NPOS;
  const unsigned short* vl0 = Vtlo + ((size_t)bh * DH + lr) * NPOS;
  const unsigned short* vl1 = vl0 + (size_t)16 * NPOS;

  f32x4 accO0 = {0.f, 0.f, 0.f, 0.f};   // d 0..15
  f32x4 accO1 = {0.f, 0.f, 0.f, 0.f};   // d 16..31
  float ssum = 0.f;

  #pragma unroll 2
  for (int t = 0; t < 8; ++t) {
    const int k0 = w * 128 + t * 16;

    // ---- QK: A = K rows k0+lr ----
    const size_t kb2 = ((size_t)bh * NPOS + k0 + lr) * DH;
    const half4 Ak_h0 = ldh4(Khi + kb2 + ko);
    const half4 Ak_h1 = ldh4(Khi + kb2 + 16 + ko);
    const half4 Ak_l0 = ldh4(Klo + kb2 + ko);
    const half4 Ak_l1 = ldh4(Klo + kb2 + 16 + ko);

    f32x4 acc = {0.f, 0.f, 0.f, 0.f};
    acc = MFMA16(Ak_h0, Bq_h0, acc);
    acc = MFMA16(Ak_h1, Bq_h1, acc);
    acc = MFMA16(Ak_h0, Bq_l0, acc);
    acc = MFMA16(Ak_h1, Bq_l1, acc);
    acc = MFMA16(Ak_l0, Bq_h0, acc);
    acc = MFMA16(Ak_l1, Bq_h1, acc);
    // acc[r] = S[q=q0+lr][k = k0+4*lg+r]

    // ---- KAN + exp(kan - Bnd) on 4 values; keep f16-consistent p ----
    unsigned short ph[4];
    #pragma unroll
    for (int r = 0; r < 4; ++r) {
      float s = acc[r];
      s = fminf(fmaxf(s, -6.0f), 6.0f);
      float e   = __expf(-s);
      float sil = s * __builtin_amdgcn_rcpf(1.0f + e);
      float tt  = fmaf(s, (1.0f / 2.4f), 2.5f);   // (s+6)/2.4 in [0,5]
      float cf  = fminf(floorf(tt), 4.0f);
      float u   = tt - cf;
      float a0 = A0[0], a1 = A1[0], a2 = A2[0], a3 = A3[0];
      a0 = cf >= 0.5f ? A0[1] : a0;  a1 = cf >= 0.5f ? A1[1] : a1;
      a2 = cf >= 0.5f ? A2[1] : a2;  a3 = cf >= 0.5f ? A3[1] : a3;
      a0 = cf >= 1.5f ? A0[2] : a0;  a1 = cf >= 1.5f ? A1[2] : a1;
      a2 = cf >= 1.5f ? A2[2] : a2;  a3 = cf >= 1.5f ? A3[2] : a3;
      a0 = cf >= 2.5f ? A0[3] : a0;  a1 = cf >= 2.5f ? A1[3] : a1;
      a2 = cf >= 2.5f ? A2[3] : a2;  a3 = cf >= 2.5f ? A3[3] : a3;
      a0 = cf >= 3.5f ? A0[4] : a0;  a1 = cf >= 3.5f ? A1[4] : a1;
      a2 = cf >= 3.5f ? A2[4] : a2;  a3 = cf >= 3.5f ? A3[4] : a3;
      float spl = fmaf(fmaf(fmaf(a3, u, a2), u, a1), u, a0);  // includes -Bnd
      float kan = fmaf(bw, sil, spl);
      unsigned short pu = f2h(__expf(kan));
      ph[r] = pu;
      ssum += h2f(pu);          // SAME rounded value PV consumes
    }
    union { half4 v; unsigned int u[2]; } Pb;
    Pb.u[0] = (unsigned int)ph[0] | ((unsigned int)ph[1] << 16);
    Pb.u[1] = (unsigned int)ph[2] | ((unsigned int)ph[3] << 16);
    // Pb is the B-operand fragment: col q = lr, k-elem j = key k0+4*lg+j

    // ---- PV: O^T += V^T · P^T  (A = V^T rows d=lr / 16+lr) ----
    const half4 Av_h0 = ldh4(vh0 + k0 + ko);
    const half4 Av_l0 = ldh4(vl0 + k0 + ko);
    const half4 Av_h1 = ldh4(vh1 + k0 + ko);
    const half4 Av_l1 = ldh4(vl1 + k0 + ko);
    accO0 = MFMA16(Av_h0, Pb.v, accO0);
    accO0 = MFMA16(Av_l0, Pb.v, accO0);
    accO1 = MFMA16(Av_h1, Pb.v, accO1);
    accO1 = MFMA16(Av_l1, Pb.v, accO1);
  }

  // ---- 8-way combine ----
  #pragma unroll
  for (int r = 0; r < 4; ++r) {
    DlO[w][4 * lg + r][lr]      = accO0[r];   // accO[r]: d = 4*lg+r, q = lr
    DlO[w][16 + 4 * lg + r][lr] = accO1[r];
  }
  DlS[w][lg][lr] = ssum;
  __syncthreads();

  {
    const int q = tid & 15;
    const int d = tid >> 4;     // 0..31 (512 threads)
    float o = 0.f, sden = 0.f;
    #pragma unroll
    for (int ww = 0; ww < 8; ++ww) {
      o += DlO[ww][d][q];
      #pragma unroll
      for (int g = 0; g < 4; ++g) sden += DlS[ww][g][q];
    }
    Onorm[((size_t)bh * DH + d) * NPOS + q0 + q] = o / sden;
  }
}

// ---------------------------------------------------------------------------
// Kernel C: output projection, 8-wave WG, 1024 WGs: 4 c-pairs x 2 i-halves
// -> 2 scalar streams/wave, 100% occupancy.
// out[b,c,n] = sum_i Wo[c,i] * Onorm[b*128+i][n]; Wo via s_loads.
// ---------------------------------------------------------------------------
__global__ __launch_bounds__(512) void outproj_kernel(
    const float* __restrict__ Onorm, const float* __restrict__ Wo,
    float* __restrict__ out)
{
  __shared__ float part[4][2][64];   // [c-group][acc][lane], 2 KB

  const int tid  = threadIdx.x;
  const int lane = tid & 63;
  const int wid  = __builtin_amdgcn_readfirstlane(tid >> 6); // 0..7 SGPR
  const int it   = wid & 3;
  const int kh   = wid >> 2;
  const int n    = blockIdx.x * 64 + lane;
  const int c0   = blockIdx.y * 8 + it * 2;   // wave-uniform SGPR
  const int b    = blockIdx.z;

  const float* ob = Onorm + (size_t)b * INNER * NPOS + n;
  const float* w0 = Wo + (size_t)c0 * INNER;

  float acc0 = 0.f, acc1 = 0.f;

  const int ibase = kh * 64;
  #pragma unroll 16
  for (int ii = 0; ii < 64; ++ii) {
    const int i = ibase + ii;
    const float xv = ob[(size_t)i * NPOS];
    acc0 += w0[i]         * xv;
    acc1 += w0[INNER + i] * xv;
  }

  if (kh == 1) {
    part[it][0][lane] = acc0;
    part[it][1][lane] = acc1;
  }
  __syncthreads();
  if (kh == 1) return;

  acc0 += part[it][0][lane];
  acc1 += part[it][1][lane];

  out[((size_t)(b * CH + c0 + 0)) * NPOS + n] = acc0;
  out[((size_t)(b * CH + c0 + 1)) * NPOS + n] = acc1;
}

// ---------------------------------------------------------------------------
extern "C" void kernel_launch(void* const* d_in, const int* in_sizes, int n_in,
                              void* d_out, int out_size, void* d_ws, size_t ws_size,
                              hipStream_t stream)
{
  const float* x  = (const float*)d_in[0];
  const float* Wq = (const float*)d_in[1];
  const float* Wk = (const float*)d_in[2];
  const float* Wv = (const float*)d_in[3];
  const float* Wo = (const float*)d_in[4];
  const float* bw = (const float*)d_in[5];
  const float* sw = (const float*)d_in[6];
  const float* ss = (const float*)d_in[7];
  float* out = (float*)d_out;

  // workspace: Onorm (f32, 1MB) | 6x f16 QKV (512KB each)
  float* Onorm = (float*)d_ws;
  unsigned short* base = (unsigned short*)(Onorm + (size_t)NBH * DH * NPOS);
  const size_t QKN = (size_t)NBH * NPOS * DH;   // 262144 elements
  unsigned short* Qhi  = base;
  unsigned short* Qlo  = Qhi  + QKN;
  unsigned short* Khi  = Qlo  + QKN;
  unsigned short* Klo  = Khi  + QKN;
  unsigned short* Vthi = Klo  + QKN;
  unsigned short* Vtlo = Vthi + QKN;

  proj_kernel<<<dim3(16, 32, 2), 512, 0, stream>>>(
      x, Wq, Wk, Wv, Qhi, Qlo, Khi, Klo, Vthi, Vtlo);
  attn_fused<<<dim3(8, 64), 512, 0, stream>>>(
      Qhi, Qlo, Khi, Klo, Vthi, Vtlo, bw, sw, ss, Onorm);
  outproj_kernel<<<dim3(16, 32, 2), 512, 0, stream>>>(Onorm, Wo, out);
}

// Round 16
// 43.658 us; speedup vs baseline: 1.1619x; 1.1619x over previous
//
#include <hip/hip_runtime.h>
#include <math.h>

#define NPOS 1024   // H*W
#define DH   32     // dim head
#define NBH  8      // B * HEADS
#define CH   256
#define INNER 128   // HEADS*DIM_HEAD

typedef __attribute__((ext_vector_type(4))) _Float16 half4;
typedef __attribute__((ext_vector_type(4))) float f32x4;

// Canonical CDNA 16x16x16 f16 MFMA.  A: row=l&15, k=4*(l>>4)+j.  B: col=l&15,
// same k ordering.  C/D: col=l&15, row=(l>>4)*4+reg.   (HW-verified by the
// passing attn_fused kernel, R9-R15.)
#define MFMA16(a, b, c) __builtin_amdgcn_mfma_f32_16x16x16f16((a), (b), (c), 0, 0, 0)

union h2u { _Float16 h; unsigned short u; };

__device__ __forceinline__ unsigned short f2h(float f) {
  h2u c; c.h = (_Float16)f; return c.u;
}
__device__ __forceinline__ float h2f(unsigned short u) {
  h2u c; c.u = u; return (float)c.h;
}
__device__ __forceinline__ half4 ldh4(const unsigned short* __restrict__ p) {
  union { half4 v; uint2 u; } r;
  r.u = *(const uint2*)p;
  return r.v;
}
// build half4 fragment pair (hi, lo) from 4 f32 values
__device__ __forceinline__ void split4(const float* v, half4& hi, half4& lo) {
  unsigned short h[4], lw[4];
  #pragma unroll
  for (int j = 0; j < 4; ++j) {
    h[j]  = f2h(v[j]);
    lw[j] = f2h(v[j] - h2f(h[j]));
  }
  union { half4 v4; unsigned int u[2]; } H, L;
  H.u[0] = (unsigned int)h[0]  | ((unsigned int)h[1]  << 16);
  H.u[1] = (unsigned int)h[2]  | ((unsigned int)h[3]  << 16);
  L.u[0] = (unsigned int)lw[0] | ((unsigned int)lw[1] << 16);
  L.u[1] = (unsigned int)lw[2] | ((unsigned int)lw[3] << 16);
  hi = H.v4;  lo = L.v4;
}

// ---------------------------------------------------------------------------
// Kernel A: QKV projection as split-f16 MFMA GEMM + hi/lo encode.
// Job = (b, itile, ntile): 16x16 output tile of all three matrices, K=256.
// 4-way K-split across waves; LDS partial combine (R12 pattern).
// A=W: row i=l&15, k-chunk float4 + on-the-fly split.  B=x: col n=l&15,
// 4 strided dword loads + split.  One x fragment feeds 9 MFMAs (Q,K,V).
// D: rows i = lg*4+r (4 contiguous d -> 8B packed Q/K stores), col n = l&15.
// Qhi/Qlo/Khi/Klo: [bh][n][d]; Vthi/Vtlo: [bh][d][n].  Q pre-scaled.
// ---------------------------------------------------------------------------
__global__ __launch_bounds__(512) void proj_kernel(
    const float* __restrict__ x, const float* __restrict__ Wq,
    const float* __restrict__ Wk, const float* __restrict__ Wv,
    unsigned short* __restrict__ Qhi, unsigned short* __restrict__ Qlo,
    unsigned short* __restrict__ Khi, unsigned short* __restrict__ Klo,
    unsigned short* __restrict__ Vthi, unsigned short* __restrict__ Vtlo)
{
  __shared__ float part[2][3][12][64];   // [job-local][kq-1][acc12][lane] 18KB

  const int tid = threadIdx.x;
  const int l   = tid & 63;
  const int wid = __builtin_amdgcn_readfirstlane(tid >> 6); // 0..7 SGPR
  const int jl  = wid >> 2;        // job within WG (0..1)
  const int kq  = wid & 3;         // K quarter (0..3)

  const int job   = blockIdx.x * 2 + jl;   // 0..1023
  const int b     = job >> 9;
  const int itile = (job >> 6) & 7;
  const int ntile = job & 63;

  const int lr = l & 15;
  const int lg = l >> 4;
  const int i_row = itile * 16 + lr;       // A-operand row (W row)
  const int gn    = ntile * 16 + lr;       // B-operand col (n)

  const float* xb = x + (size_t)b * CH * NPOS;
  const float* wqr = Wq + (size_t)i_row * CH;
  const float* wkr = Wk + (size_t)i_row * CH;
  const float* wvr = Wv + (size_t)i_row * CH;

  f32x4 aq = {0.f,0.f,0.f,0.f}, ak = {0.f,0.f,0.f,0.f}, av = {0.f,0.f,0.f,0.f};

  #pragma unroll
  for (int kk = 0; kk < 4; ++kk) {
    const int cb = kq * 64 + kk * 16 + lg * 4;   // this lane's k base

    // ---- B fragment from x (4 strided loads, split f16) ----
    float xv[4];
    #pragma unroll
    for (int j = 0; j < 4; ++j) xv[j] = xb[(size_t)(cb + j) * NPOS + gn];
    half4 Bhi, Blo;
    split4(xv, Bhi, Blo);

    // ---- A fragments from W (float4 + split), 3 MFMAs each ----
    {
      float4 wv4 = *(const float4*)(wqr + cb);
      float wv[4] = {wv4.x, wv4.y, wv4.z, wv4.w};
      half4 Ahi, Alo;  split4(wv, Ahi, Alo);
      aq = MFMA16(Ahi, Bhi, aq);
      aq = MFMA16(Ahi, Blo, aq);
      aq = MFMA16(Alo, Bhi, aq);
    }
    {
      float4 wv4 = *(const float4*)(wkr + cb);
      float wv[4] = {wv4.x, wv4.y, wv4.z, wv4.w};
      half4 Ahi, Alo;  split4(wv, Ahi, Alo);
      ak = MFMA16(Ahi, Bhi, ak);
      ak = MFMA16(Ahi, Blo, ak);
      ak = MFMA16(Alo, Bhi, ak);
    }
    {
      float4 wv4 = *(const float4*)(wvr + cb);
      float wv[4] = {wv4.x, wv4.y, wv4.z, wv4.w};
      half4 Ahi, Alo;  split4(wv, Ahi, Alo);
      av = MFMA16(Ahi, Bhi, av);
      av = MFMA16(Ahi, Blo, av);
      av = MFMA16(Alo, Bhi, av);
    }
  }

  // ---- K-split combine via LDS ----
  if (kq > 0) {
    #pragma unroll
    for (int r = 0; r < 4; ++r) {
      part[jl][kq - 1][r][l]     = aq[r];
      part[jl][kq - 1][4 + r][l] = ak[r];
      part[jl][kq - 1][8 + r][l] = av[r];
    }
  }
  __syncthreads();
  if (kq > 0) return;

  #pragma unroll
  for (int p = 0; p < 3; ++p)
    #pragma unroll
    for (int r = 0; r < 4; ++r) {
      aq[r] += part[jl][p][r][l];
      ak[r] += part[jl][p][4 + r][l];
      av[r] += part[jl][p][8 + r][l];
    }

  // ---- encode hi/lo f16 and store ----
  const float qs = 0.17677669529663687f;  // 1/sqrt(32)
  const int h  = itile >> 1;
  const int bh = b * 4 + h;
  const int d0 = (itile & 1) * 16 + lg * 4;   // 4 contiguous d per lane

  unsigned short qh[4], ql[4], kh[4], kl[4], vh[4], vl[4];
  #pragma unroll
  for (int r = 0; r < 4; ++r) {
    float q = aq[r] * qs;
    qh[r] = f2h(q);   ql[r] = f2h(q - h2f(qh[r]));
    kh[r] = f2h(ak[r]); kl[r] = f2h(ak[r] - h2f(kh[r]));
    vh[r] = f2h(av[r]); vl[r] = f2h(av[r] - h2f(vh[r]));
  }

  const size_t qk = ((size_t)bh * NPOS + gn) * DH + d0;   // 8B aligned
  *(uint2*)(Qhi + qk) = make_uint2((unsigned)qh[0] | ((unsigned)qh[1] << 16),
                                   (unsigned)qh[2] | ((unsigned)qh[3] << 16));
  *(uint2*)(Qlo + qk) = make_uint2((unsigned)ql[0] | ((unsigned)ql[1] << 16),
                                   (unsigned)ql[2] | ((unsigned)ql[3] << 16));
  *(uint2*)(Khi + qk) = make_uint2((unsigned)kh[0] | ((unsigned)kh[1] << 16),
                                   (unsigned)kh[2] | ((unsigned)kh[3] << 16));
  *(uint2*)(Klo + qk) = make_uint2((unsigned)kl[0] | ((unsigned)kl[1] << 16),
                                   (unsigned)kl[2] | ((unsigned)kl[3] << 16));

  #pragma unroll
  for (int r = 0; r < 4; ++r) {
    const size_t vt = ((size_t)bh * DH + d0 + r) * NPOS + gn;
    Vthi[vt] = vh[r];
    Vtlo[vt] = vl[r];
  }
}

// ---------------------------------------------------------------------------
// Kernel B: fully fused attention (UNCHANGED from passing R9-R15 version).
// S^T = K·Q^T; KAN + exp(kan-Bnd) in-register; f16 P = B-operand fragment
// for O^T = V^T·P^T; denominator sums same f16-rounded p; 8-way LDS combine.
// ---------------------------------------------------------------------------
__global__ __launch_bounds__(512) void attn_fused(
    const unsigned short* __restrict__ Qhi, const unsigned short* __restrict__ Qlo,
    const unsigned short* __restrict__ Khi, const unsigned short* __restrict__ Klo,
    const unsigned short* __restrict__ Vthi, const unsigned short* __restrict__ Vtlo,
    const float* __restrict__ bwp, const float* __restrict__ swp,
    const float* __restrict__ ssp, float* __restrict__ Onorm)
{
  __shared__ float DlO[8][32][17];
  __shared__ float DlS[8][4][17];

  const int tid = threadIdx.x;
  const int l   = tid & 63;
  const int w   = tid >> 6;        // 0..7
  const int lr  = l & 15;
  const int lg  = l >> 4;          // 0..3
  const int ko  = lg * 4;
  const int bh  = blockIdx.x;      // 0..7 (== XCD)
  const int q0  = blockIdx.y * 16;

  // ---- uniform KAN constants ----
  const float sc = ssp[0];
  const float bw = bwp[0];
  float C[8];
  #pragma unroll
  for (int j = 0; j < 8; ++j) C[j] = swp[j] * sc;
  float maxc = 0.f;
  #pragma unroll
  for (int j = 0; j < 8; ++j) maxc = fmaxf(maxc, fabsf(C[j]));
  const float Bnd = fabsf(bw) * 6.0f + maxc;    // >= max_x kan(x)

  float A0[5], A1[5], A2[5], A3[5];             // per-cell cubic; -Bnd in A0
  #pragma unroll
  for (int c = 0; c < 5; ++c) {
    A0[c] = (C[c] + 4.f * C[c+1] + C[c+2]) * (1.f / 6.f) - Bnd;
    A1[c] = (-3.f * C[c] + 3.f * C[c+2]) * (1.f / 6.f);
    A2[c] = (3.f * C[c] - 6.f * C[c+1] + 3.f * C[c+2]) * (1.f / 6.f);
    A3[c] = (-C[c] + 3.f * C[c+1] - 3.f * C[c+2] + C[c+3]) * (1.f / 6.f);
  }

  // ---- Q fragments (B-operand, persistent): col q = q0+lr, k-dim d ----
  const size_t qb = ((size_t)bh * NPOS + q0 + lr) * DH;
  const half4 Bq_h0 = ldh4(Qhi + qb + ko);
  const half4 Bq_h1 = ldh4(Qhi + qb + 16 + ko);
  const half4 Bq_l0 = ldh4(Qlo + qb + ko);
  const half4 Bq_l1 = ldh4(Qlo + qb + 16 + ko);

  // ---- V^T bases (A-operand): row d = lr (+16), k = key ----
  const unsigned short* vh0 = Vthi + ((size_t)bh * DH + lr) * NPOS;
  const unsigned short* vh1 = vh0 + (size_t)16 * NPOS;
  const unsigned short* vl0 = Vtlo + ((size_t)bh * DH + lr) * NPOS;
  const unsigned short* vl1 = vl0 + (size_t)16 * NPOS;

  f32x4 accO0 = {0.f, 0.f, 0.f, 0.f};   // d 0..15
  f32x4 accO1 = {0.f, 0.f, 0.f, 0.f};   // d 16..31
  float ssum = 0.f;

  #pragma unroll 2
  for (int t = 0; t < 8; ++t) {
    const int k0 = w * 128 + t * 16;

    // ---- QK: A = K rows k0+lr ----
    const size_t kb2 = ((size_t)bh * NPOS + k0 + lr) * DH;
    const half4 Ak_h0 = ldh4(Khi + kb2 + ko);
    const half4 Ak_h1 = ldh4(Khi + kb2 + 16 + ko);
    const half4 Ak_l0 = ldh4(Klo + kb2 + ko);
    const half4 Ak_l1 = ldh4(Klo + kb2 + 16 + ko);

    f32x4 acc = {0.f, 0.f, 0.f, 0.f};
    acc = MFMA16(Ak_h0, Bq_h0, acc);
    acc = MFMA16(Ak_h1, Bq_h1, acc);
    acc = MFMA16(Ak_h0, Bq_l0, acc);
    acc = MFMA16(Ak_h1, Bq_l1, acc);
    acc = MFMA16(Ak_l0, Bq_h0, acc);
    acc = MFMA16(Ak_l1, Bq_h1, acc);
    // acc[r] = S[q=q0+lr][k = k0+4*lg+r]

    // ---- KAN + exp(kan - Bnd) on 4 values; keep f16-consistent p ----
    unsigned short ph[4];
    #pragma unroll
    for (int r = 0; r < 4; ++r) {
      float s = acc[r];
      s = fminf(fmaxf(s, -6.0f), 6.0f);
      float e   = __expf(-s);
      float sil = s * __builtin_amdgcn_rcpf(1.0f + e);
      float tt  = fmaf(s, (1.0f / 2.4f), 2.5f);   // (s+6)/2.4 in [0,5]
      float cf  = fminf(floorf(tt), 4.0f);
      float u   = tt - cf;
      float a0 = A0[0], a1 = A1[0], a2 = A2[0], a3 = A3[0];
      a0 = cf >= 0.5f ? A0[1] : a0;  a1 = cf >= 0.5f ? A1[1] : a1;
      a2 = cf >= 0.5f ? A2[1] : a2;  a3 = cf >= 0.5f ? A3[1] : a3;
      a0 = cf >= 1.5f ? A0[2] : a0;  a1 = cf >= 1.5f ? A1[2] : a1;
      a2 = cf >= 1.5f ? A2[2] : a2;  a3 = cf >= 1.5f ? A3[2] : a3;
      a0 = cf >= 2.5f ? A0[3] : a0;  a1 = cf >= 2.5f ? A1[3] : a1;
      a2 = cf >= 2.5f ? A2[3] : a2;  a3 = cf >= 2.5f ? A3[3] : a3;
      a0 = cf >= 3.5f ? A0[4] : a0;  a1 = cf >= 3.5f ? A1[4] : a1;
      a2 = cf >= 3.5f ? A2[4] : a2;  a3 = cf >= 3.5f ? A3[4] : a3;
      float spl = fmaf(fmaf(fmaf(a3, u, a2), u, a1), u, a0);  // includes -Bnd
      float kan = fmaf(bw, sil, spl);
      unsigned short pu = f2h(__expf(kan));
      ph[r] = pu;
      ssum += h2f(pu);          // SAME rounded value PV consumes
    }
    union { half4 v; unsigned int u[2]; } Pb;
    Pb.u[0] = (unsigned int)ph[0] | ((unsigned int)ph[1] << 16);
    Pb.u[1] = (unsigned int)ph[2] | ((unsigned int)ph[3] << 16);
    // Pb is the B-operand fragment: col q = lr, k-elem j = key k0+4*lg+j

    // ---- PV: O^T += V^T · P^T  (A = V^T rows d=lr / 16+lr) ----
    const half4 Av_h0 = ldh4(vh0 + k0 + ko);
    const half4 Av_l0 = ldh4(vl0 + k0 + ko);
    const half4 Av_h1 = ldh4(vh1 + k0 + ko);
    const half4 Av_l1 = ldh4(vl1 + k0 + ko);
    accO0 = MFMA16(Av_h0, Pb.v, accO0);
    accO0 = MFMA16(Av_l0, Pb.v, accO0);
    accO1 = MFMA16(Av_h1, Pb.v, accO1);
    accO1 = MFMA16(Av_l1, Pb.v, accO1);
  }

  // ---- 8-way combine ----
  #pragma unroll
  for (int r = 0; r < 4; ++r) {
    DlO[w][4 * lg + r][lr]      = accO0[r];   // accO[r]: d = 4*lg+r, q = lr
    DlO[w][16 + 4 * lg + r][lr] = accO1[r];
  }
  DlS[w][lg][lr] = ssum;
  __syncthreads();

  {
    const int q = tid & 15;
    const int d = tid >> 4;     // 0..31 (512 threads)
    float o = 0.f, sden = 0.f;
    #pragma unroll
    for (int ww = 0; ww < 8; ++ww) {
      o += DlO[ww][d][q];
      #pragma unroll
      for (int g = 0; g < 4; ++g) sden += DlS[ww][g][q];
    }
    Onorm[((size_t)bh * DH + d) * NPOS + q0 + q] = o / sden;
  }
}

// ---------------------------------------------------------------------------
// Kernel C: output projection (R12 version: 4 c-groups x 2 i-halves).
// out[b,c,n] = sum_i Wo[c,i] * Onorm[b*128+i][n]; Wo via s_loads.
// ---------------------------------------------------------------------------
__global__ __launch_bounds__(512) void outproj_kernel(
    const float* __restrict__ Onorm, const float* __restrict__ Wo,
    float* __restrict__ out)
{
  __shared__ float part[4][4][64];   // [c-group][acc][lane], 4 KB

  const int tid  = threadIdx.x;
  const int lane = tid & 63;
  const int wid  = __builtin_amdgcn_readfirstlane(tid >> 6); // 0..7 SGPR
  const int it   = wid & 3;
  const int kh   = wid >> 2;
  const int n    = blockIdx.x * 64 + lane;
  const int c0   = blockIdx.y * 16 + it * 4;   // wave-uniform SGPR
  const int b    = blockIdx.z;

  const float* ob = Onorm + (size_t)b * INNER * NPOS + n;
  const float* w0 = Wo + (size_t)c0 * INNER;

  float acc[4] = {0.f, 0.f, 0.f, 0.f};

  const int ibase = kh * 64;
  #pragma unroll 16
  for (int ii = 0; ii < 64; ++ii) {
    const int i = ibase + ii;
    const float xv = ob[(size_t)i * NPOS];
    acc[0] += w0[i]             * xv;
    acc[1] += w0[INNER + i]     * xv;
    acc[2] += w0[2 * INNER + i] * xv;
    acc[3] += w0[3 * INNER + i] * xv;
  }

  if (kh == 1) {
    #pragma unroll
    for (int j = 0; j < 4; ++j) part[it][j][lane] = acc[j];
  }
  __syncthreads();
  if (kh == 1) return;

  #pragma unroll
  for (int j = 0; j < 4; ++j) acc[j] += part[it][j][lane];

  #pragma unroll
  for (int j = 0; j < 4; ++j)
    out[((size_t)(b * CH + c0 + j)) * NPOS + n] = acc[j];
}

// ---------------------------------------------------------------------------
extern "C" void kernel_launch(void* const* d_in, const int* in_sizes, int n_in,
                              void* d_out, int out_size, void* d_ws, size_t ws_size,
                              hipStream_t stream)
{
  const float* x  = (const float*)d_in[0];
  const float* Wq = (const float*)d_in[1];
  const float* Wk = (const float*)d_in[2];
  const float* Wv = (const float*)d_in[3];
  const float* Wo = (const float*)d_in[4];
  const float* bw = (const float*)d_in[5];
  const float* sw = (const float*)d_in[6];
  const float* ss = (const float*)d_in[7];
  float* out = (float*)d_out;

  // workspace: Onorm (f32, 1MB) | 6x f16 QKV (512KB each)
  float* Onorm = (float*)d_ws;
  unsigned short* base = (unsigned short*)(Onorm + (size_t)NBH * DH * NPOS);
  const size_t QKN = (size_t)NBH * NPOS * DH;   // 262144 elements
  unsigned short* Qhi  = base;
  unsigned short* Qlo  = Qhi  + QKN;
  unsigned short* Khi  = Qlo  + QKN;
  unsigned short* Klo  = Khi  + QKN;
  unsigned short* Vthi = Klo  + QKN;
  unsigned short* Vtlo = Vthi + QKN;

  proj_kernel<<<dim3(512), 512, 0, stream>>>(
      x, Wq, Wk, Wv, Qhi, Qlo, Khi, Klo, Vthi, Vtlo);
  attn_fused<<<dim3(8, 64), 512, 0, stream>>>(
      Qhi, Qlo, Khi, Klo, Vthi, Vtlo, bw, sw, ss, Onorm);
  outproj_kernel<<<dim3(16, 16, 2), 512, 0, stream>>>(Onorm, Wo, out);
}

// Round 17
// 43.198 us; speedup vs baseline: 1.1743x; 1.0107x over previous
//
#include <hip/hip_runtime.h>
#include <math.h>

#define NPOS 1024   // H*W
#define DH   32     // dim head
#define NBH  8      // B * HEADS
#define CH   256
#define INNER 128   // HEADS*DIM_HEAD

typedef __attribute__((ext_vector_type(4))) _Float16 half4;
typedef __attribute__((ext_vector_type(4))) float f32x4;

// Canonical CDNA 16x16x16 f16 MFMA.  A: row=l&15, k=4*(l>>4)+j.  B: col=l&15,
// same k ordering.  C/D: col=l&15, row=(l>>4)*4+reg.   (HW-verified by the
// passing attn_fused kernel, R9-R16.)
#define MFMA16(a, b, c) __builtin_amdgcn_mfma_f32_16x16x16f16((a), (b), (c), 0, 0, 0)

union h2u { _Float16 h; unsigned short u; };

__device__ __forceinline__ unsigned short f2h(float f) {
  h2u c; c.h = (_Float16)f; return c.u;
}
__device__ __forceinline__ float h2f(unsigned short u) {
  h2u c; c.u = u; return (float)c.h;
}
__device__ __forceinline__ half4 ldh4(const unsigned short* __restrict__ p) {
  union { half4 v; uint2 u; } r;
  r.u = *(const uint2*)p;
  return r.v;
}
// build half4 fragment pair (hi, lo) from 4 f32 values
__device__ __forceinline__ void split4(const float* v, half4& hi, half4& lo) {
  unsigned short h[4], lw[4];
  #pragma unroll
  for (int j = 0; j < 4; ++j) {
    h[j]  = f2h(v[j]);
    lw[j] = f2h(v[j] - h2f(h[j]));
  }
  union { half4 v4; unsigned int u[2]; } H, L;
  H.u[0] = (unsigned int)h[0]  | ((unsigned int)h[1]  << 16);
  H.u[1] = (unsigned int)h[2]  | ((unsigned int)h[3]  << 16);
  L.u[0] = (unsigned int)lw[0] | ((unsigned int)lw[1] << 16);
  L.u[1] = (unsigned int)lw[2] | ((unsigned int)lw[3] << 16);
  hi = H.v4;  lo = L.v4;
}

// ---------------------------------------------------------------------------
// Kernel A: QKV projection as split-f16 MFMA GEMM + hi/lo encode.
// (UNCHANGED from passing R16 version.)
// ---------------------------------------------------------------------------
__global__ __launch_bounds__(512) void proj_kernel(
    const float* __restrict__ x, const float* __restrict__ Wq,
    const float* __restrict__ Wk, const float* __restrict__ Wv,
    unsigned short* __restrict__ Qhi, unsigned short* __restrict__ Qlo,
    unsigned short* __restrict__ Khi, unsigned short* __restrict__ Klo,
    unsigned short* __restrict__ Vthi, unsigned short* __restrict__ Vtlo)
{
  __shared__ float part[2][3][12][64];   // [job-local][kq-1][acc12][lane] 18KB

  const int tid = threadIdx.x;
  const int l   = tid & 63;
  const int wid = __builtin_amdgcn_readfirstlane(tid >> 6); // 0..7 SGPR
  const int jl  = wid >> 2;        // job within WG (0..1)
  const int kq  = wid & 3;         // K quarter (0..3)

  const int job   = blockIdx.x * 2 + jl;   // 0..1023
  const int b     = job >> 9;
  const int itile = (job >> 6) & 7;
  const int ntile = job & 63;

  const int lr = l & 15;
  const int lg = l >> 4;
  const int i_row = itile * 16 + lr;       // A-operand row (W row)
  const int gn    = ntile * 16 + lr;       // B-operand col (n)

  const float* xb = x + (size_t)b * CH * NPOS;
  const float* wqr = Wq + (size_t)i_row * CH;
  const float* wkr = Wk + (size_t)i_row * CH;
  const float* wvr = Wv + (size_t)i_row * CH;

  f32x4 aq = {0.f,0.f,0.f,0.f}, ak = {0.f,0.f,0.f,0.f}, av = {0.f,0.f,0.f,0.f};

  #pragma unroll
  for (int kk = 0; kk < 4; ++kk) {
    const int cb = kq * 64 + kk * 16 + lg * 4;   // this lane's k base

    // ---- B fragment from x (4 strided loads, split f16) ----
    float xv[4];
    #pragma unroll
    for (int j = 0; j < 4; ++j) xv[j] = xb[(size_t)(cb + j) * NPOS + gn];
    half4 Bhi, Blo;
    split4(xv, Bhi, Blo);

    // ---- A fragments from W (float4 + split), 3 MFMAs each ----
    {
      float4 wv4 = *(const float4*)(wqr + cb);
      float wv[4] = {wv4.x, wv4.y, wv4.z, wv4.w};
      half4 Ahi, Alo;  split4(wv, Ahi, Alo);
      aq = MFMA16(Ahi, Bhi, aq);
      aq = MFMA16(Ahi, Blo, aq);
      aq = MFMA16(Alo, Bhi, aq);
    }
    {
      float4 wv4 = *(const float4*)(wkr + cb);
      float wv[4] = {wv4.x, wv4.y, wv4.z, wv4.w};
      half4 Ahi, Alo;  split4(wv, Ahi, Alo);
      ak = MFMA16(Ahi, Bhi, ak);
      ak = MFMA16(Ahi, Blo, ak);
      ak = MFMA16(Alo, Bhi, ak);
    }
    {
      float4 wv4 = *(const float4*)(wvr + cb);
      float wv[4] = {wv4.x, wv4.y, wv4.z, wv4.w};
      half4 Ahi, Alo;  split4(wv, Ahi, Alo);
      av = MFMA16(Ahi, Bhi, av);
      av = MFMA16(Ahi, Blo, av);
      av = MFMA16(Alo, Bhi, av);
    }
  }

  // ---- K-split combine via LDS ----
  if (kq > 0) {
    #pragma unroll
    for (int r = 0; r < 4; ++r) {
      part[jl][kq - 1][r][l]     = aq[r];
      part[jl][kq - 1][4 + r][l] = ak[r];
      part[jl][kq - 1][8 + r][l] = av[r];
    }
  }
  __syncthreads();
  if (kq > 0) return;

  #pragma unroll
  for (int p = 0; p < 3; ++p)
    #pragma unroll
    for (int r = 0; r < 4; ++r) {
      aq[r] += part[jl][p][r][l];
      ak[r] += part[jl][p][4 + r][l];
      av[r] += part[jl][p][8 + r][l];
    }

  // ---- encode hi/lo f16 and store ----
  const float qs = 0.17677669529663687f;  // 1/sqrt(32)
  const int h  = itile >> 1;
  const int bh = b * 4 + h;
  const int d0 = (itile & 1) * 16 + lg * 4;   // 4 contiguous d per lane

  unsigned short qh[4], ql[4], kh[4], kl[4], vh[4], vl[4];
  #pragma unroll
  for (int r = 0; r < 4; ++r) {
    float q = aq[r] * qs;
    qh[r] = f2h(q);   ql[r] = f2h(q - h2f(qh[r]));
    kh[r] = f2h(ak[r]); kl[r] = f2h(ak[r] - h2f(kh[r]));
    vh[r] = f2h(av[r]); vl[r] = f2h(av[r] - h2f(vh[r]));
  }

  const size_t qk = ((size_t)bh * NPOS + gn) * DH + d0;   // 8B aligned
  *(uint2*)(Qhi + qk) = make_uint2((unsigned)qh[0] | ((unsigned)qh[1] << 16),
                                   (unsigned)qh[2] | ((unsigned)qh[3] << 16));
  *(uint2*)(Qlo + qk) = make_uint2((unsigned)ql[0] | ((unsigned)ql[1] << 16),
                                   (unsigned)ql[2] | ((unsigned)ql[3] << 16));
  *(uint2*)(Khi + qk) = make_uint2((unsigned)kh[0] | ((unsigned)kh[1] << 16),
                                   (unsigned)kh[2] | ((unsigned)kh[3] << 16));
  *(uint2*)(Klo + qk) = make_uint2((unsigned)kl[0] | ((unsigned)kl[1] << 16),
                                   (unsigned)kl[2] | ((unsigned)kl[3] << 16));

  #pragma unroll
  for (int r = 0; r < 4; ++r) {
    const size_t vt = ((size_t)bh * DH + d0 + r) * NPOS + gn;
    Vthi[vt] = vh[r];
    Vtlo[vt] = vl[r];
  }
}

// ---------------------------------------------------------------------------
// Kernel B: fully fused attention (UNCHANGED from passing R9-R16 version).
// S^T = K·Q^T; KAN + exp(kan-Bnd) in-register; f16 P = B-operand fragment
// for O^T = V^T·P^T; denominator sums same f16-rounded p; 8-way LDS combine.
// ---------------------------------------------------------------------------
__global__ __launch_bounds__(512) void attn_fused(
    const unsigned short* __restrict__ Qhi, const unsigned short* __restrict__ Qlo,
    const unsigned short* __restrict__ Khi, const unsigned short* __restrict__ Klo,
    const unsigned short* __restrict__ Vthi, const unsigned short* __restrict__ Vtlo,
    const float* __restrict__ bwp, const float* __restrict__ swp,
    const float* __restrict__ ssp, float* __restrict__ Onorm)
{
  __shared__ float DlO[8][32][17];
  __shared__ float DlS[8][4][17];

  const int tid = threadIdx.x;
  const int l   = tid & 63;
  const int w   = tid >> 6;        // 0..7
  const int lr  = l & 15;
  const int lg  = l >> 4;          // 0..3
  const int ko  = lg * 4;
  const int bh  = blockIdx.x;      // 0..7 (== XCD)
  const int q0  = blockIdx.y * 16;

  // ---- uniform KAN constants ----
  const float sc = ssp[0];
  const float bw = bwp[0];
  float C[8];
  #pragma unroll
  for (int j = 0; j < 8; ++j) C[j] = swp[j] * sc;
  float maxc = 0.f;
  #pragma unroll
  for (int j = 0; j < 8; ++j) maxc = fmaxf(maxc, fabsf(C[j]));
  const float Bnd = fabsf(bw) * 6.0f + maxc;    // >= max_x kan(x)

  float A0[5], A1[5], A2[5], A3[5];             // per-cell cubic; -Bnd in A0
  #pragma unroll
  for (int c = 0; c < 5; ++c) {
    A0[c] = (C[c] + 4.f * C[c+1] + C[c+2]) * (1.f / 6.f) - Bnd;
    A1[c] = (-3.f * C[c] + 3.f * C[c+2]) * (1.f / 6.f);
    A2[c] = (3.f * C[c] - 6.f * C[c+1] + 3.f * C[c+2]) * (1.f / 6.f);
    A3[c] = (-C[c] + 3.f * C[c+1] - 3.f * C[c+2] + C[c+3]) * (1.f / 6.f);
  }

  // ---- Q fragments (B-operand, persistent): col q = q0+lr, k-dim d ----
  const size_t qb = ((size_t)bh * NPOS + q0 + lr) * DH;
  const half4 Bq_h0 = ldh4(Qhi + qb + ko);
  const half4 Bq_h1 = ldh4(Qhi + qb + 16 + ko);
  const half4 Bq_l0 = ldh4(Qlo + qb + ko);
  const half4 Bq_l1 = ldh4(Qlo + qb + 16 + ko);

  // ---- V^T bases (A-operand): row d = lr (+16), k = key ----
  const unsigned short* vh0 = Vthi + ((size_t)bh * DH + lr) * NPOS;
  const unsigned short* vh1 = vh0 + (size_t)16 * NPOS;
  const unsigned short* vl0 = Vtlo + ((size_t)bh * DH + lr) * NPOS;
  const unsigned short* vl1 = vl0 + (size_t)16 * NPOS;

  f32x4 accO0 = {0.f, 0.f, 0.f, 0.f};   // d 0..15
  f32x4 accO1 = {0.f, 0.f, 0.f, 0.f};   // d 16..31
  float ssum = 0.f;

  #pragma unroll 2
  for (int t = 0; t < 8; ++t) {
    const int k0 = w * 128 + t * 16;

    // ---- QK: A = K rows k0+lr ----
    const size_t kb2 = ((size_t)bh * NPOS + k0 + lr) * DH;
    const half4 Ak_h0 = ldh4(Khi + kb2 + ko);
    const half4 Ak_h1 = ldh4(Khi + kb2 + 16 + ko);
    const half4 Ak_l0 = ldh4(Klo + kb2 + ko);
    const half4 Ak_l1 = ldh4(Klo + kb2 + 16 + ko);

    f32x4 acc = {0.f, 0.f, 0.f, 0.f};
    acc = MFMA16(Ak_h0, Bq_h0, acc);
    acc = MFMA16(Ak_h1, Bq_h1, acc);
    acc = MFMA16(Ak_h0, Bq_l0, acc);
    acc = MFMA16(Ak_h1, Bq_l1, acc);
    acc = MFMA16(Ak_l0, Bq_h0, acc);
    acc = MFMA16(Ak_l1, Bq_h1, acc);
    // acc[r] = S[q=q0+lr][k = k0+4*lg+r]

    // ---- KAN + exp(kan - Bnd) on 4 values; keep f16-consistent p ----
    unsigned short ph[4];
    #pragma unroll
    for (int r = 0; r < 4; ++r) {
      float s = acc[r];
      s = fminf(fmaxf(s, -6.0f), 6.0f);
      float e   = __expf(-s);
      float sil = s * __builtin_amdgcn_rcpf(1.0f + e);
      float tt  = fmaf(s, (1.0f / 2.4f), 2.5f);   // (s+6)/2.4 in [0,5]
      float cf  = fminf(floorf(tt), 4.0f);
      float u   = tt - cf;
      float a0 = A0[0], a1 = A1[0], a2 = A2[0], a3 = A3[0];
      a0 = cf >= 0.5f ? A0[1] : a0;  a1 = cf >= 0.5f ? A1[1] : a1;
      a2 = cf >= 0.5f ? A2[1] : a2;  a3 = cf >= 0.5f ? A3[1] : a3;
      a0 = cf >= 1.5f ? A0[2] : a0;  a1 = cf >= 1.5f ? A1[2] : a1;
      a2 = cf >= 1.5f ? A2[2] : a2;  a3 = cf >= 1.5f ? A3[2] : a3;
      a0 = cf >= 2.5f ? A0[3] : a0;  a1 = cf >= 2.5f ? A1[3] : a1;
      a2 = cf >= 2.5f ? A2[3] : a2;  a3 = cf >= 2.5f ? A3[3] : a3;
      a0 = cf >= 3.5f ? A0[4] : a0;  a1 = cf >= 3.5f ? A1[4] : a1;
      a2 = cf >= 3.5f ? A2[4] : a2;  a3 = cf >= 3.5f ? A3[4] : a3;
      float spl = fmaf(fmaf(fmaf(a3, u, a2), u, a1), u, a0);  // includes -Bnd
      float kan = fmaf(bw, sil, spl);
      unsigned short pu = f2h(__expf(kan));
      ph[r] = pu;
      ssum += h2f(pu);          // SAME rounded value PV consumes
    }
    union { half4 v; unsigned int u[2]; } Pb;
    Pb.u[0] = (unsigned int)ph[0] | ((unsigned int)ph[1] << 16);
    Pb.u[1] = (unsigned int)ph[2] | ((unsigned int)ph[3] << 16);
    // Pb is the B-operand fragment: col q = lr, k-elem j = key k0+4*lg+j

    // ---- PV: O^T += V^T · P^T  (A = V^T rows d=lr / 16+lr) ----
    const half4 Av_h0 = ldh4(vh0 + k0 + ko);
    const half4 Av_l0 = ldh4(vl0 + k0 + ko);
    const half4 Av_h1 = ldh4(vh1 + k0 + ko);
    const half4 Av_l1 = ldh4(vl1 + k0 + ko);
    accO0 = MFMA16(Av_h0, Pb.v, accO0);
    accO0 = MFMA16(Av_l0, Pb.v, accO0);
    accO1 = MFMA16(Av_h1, Pb.v, accO1);
    accO1 = MFMA16(Av_l1, Pb.v, accO1);
  }

  // ---- 8-way combine ----
  #pragma unroll
  for (int r = 0; r < 4; ++r) {
    DlO[w][4 * lg + r][lr]      = accO0[r];   // accO[r]: d = 4*lg+r, q = lr
    DlO[w][16 + 4 * lg + r][lr] = accO1[r];
  }
  DlS[w][lg][lr] = ssum;
  __syncthreads();

  {
    const int q = tid & 15;
    const int d = tid >> 4;     // 0..31 (512 threads)
    float o = 0.f, sden = 0.f;
    #pragma unroll
    for (int ww = 0; ww < 8; ++ww) {
      o += DlO[ww][d][q];
      #pragma unroll
      for (int g = 0; g < 4; ++g) sden += DlS[ww][g][q];
    }
    Onorm[((size_t)bh * DH + d) * NPOS + q0 + q] = o / sden;
  }
}

// ---------------------------------------------------------------------------
// Kernel C: output projection as split-f16 MFMA GEMM.
// Job = (b, ctile, ntile): 16x16 tile, K=128.  2 jobs/WG x 4-way K-split.
// A=Wo (row c, float4+split), B=Onorm (col n, strided dwords+split).
// D: rows c = lg*4+r, col n = lr -> coalesced f32 stores.
// ---------------------------------------------------------------------------
__global__ __launch_bounds__(512) void outproj_kernel(
    const float* __restrict__ Onorm, const float* __restrict__ Wo,
    float* __restrict__ out)
{
  __shared__ float part[2][3][4][64];   // [job-local][kq-1][acc][lane], 6 KB

  const int tid = threadIdx.x;
  const int l   = tid & 63;
  const int wid = __builtin_amdgcn_readfirstlane(tid >> 6); // 0..7 SGPR
  const int jl  = wid >> 2;        // job within WG (0..1)
  const int kq  = wid & 3;         // K quarter (0..3), 32 i each

  const int job   = blockIdx.x * 2 + jl;   // 0..2047
  const int b     = job >> 10;
  const int ctile = (job >> 6) & 15;
  const int ntile = job & 63;

  const int lr = l & 15;
  const int lg = l >> 4;
  const int c_row = ctile * 16 + lr;       // A-operand row (Wo row)
  const int gn    = ntile * 16 + lr;       // B-operand col (n)

  const float* ob = Onorm + (size_t)b * INNER * NPOS;
  const float* wr = Wo + (size_t)c_row * INNER;

  f32x4 acc = {0.f, 0.f, 0.f, 0.f};

  #pragma unroll
  for (int kk = 0; kk < 2; ++kk) {
    const int ib = kq * 32 + kk * 16 + lg * 4;   // this lane's i base

    float xv[4];
    #pragma unroll
    for (int j = 0; j < 4; ++j) xv[j] = ob[(size_t)(ib + j) * NPOS + gn];
    half4 Bhi, Blo;
    split4(xv, Bhi, Blo);

    float4 wv4 = *(const float4*)(wr + ib);
    float wv[4] = {wv4.x, wv4.y, wv4.z, wv4.w};
    half4 Ahi, Alo;
    split4(wv, Ahi, Alo);

    acc = MFMA16(Ahi, Bhi, acc);
    acc = MFMA16(Ahi, Blo, acc);
    acc = MFMA16(Alo, Bhi, acc);
  }

  if (kq > 0) {
    #pragma unroll
    for (int r = 0; r < 4; ++r) part[jl][kq - 1][r][l] = acc[r];
  }
  __syncthreads();
  if (kq > 0) return;

  #pragma unroll
  for (int p = 0; p < 3; ++p)
    #pragma unroll
    for (int r = 0; r < 4; ++r) acc[r] += part[jl][p][r][l];

  #pragma unroll
  for (int r = 0; r < 4; ++r) {
    const int c = ctile * 16 + lg * 4 + r;
    out[((size_t)(b * CH + c)) * NPOS + gn] = acc[r];
  }
}

// ---------------------------------------------------------------------------
extern "C" void kernel_launch(void* const* d_in, const int* in_sizes, int n_in,
                              void* d_out, int out_size, void* d_ws, size_t ws_size,
                              hipStream_t stream)
{
  const float* x  = (const float*)d_in[0];
  const float* Wq = (const float*)d_in[1];
  const float* Wk = (const float*)d_in[2];
  const float* Wv = (const float*)d_in[3];
  const float* Wo = (const float*)d_in[4];
  const float* bw = (const float*)d_in[5];
  const float* sw = (const float*)d_in[6];
  const float* ss = (const float*)d_in[7];
  float* out = (float*)d_out;

  // workspace: Onorm (f32, 1MB) | 6x f16 QKV (512KB each)
  float* Onorm = (float*)d_ws;
  unsigned short* base = (unsigned short*)(Onorm + (size_t)NBH * DH * NPOS);
  const size_t QKN = (size_t)NBH * NPOS * DH;   // 262144 elements
  unsigned short* Qhi  = base;
  unsigned short* Qlo  = Qhi  + QKN;
  unsigned short* Khi  = Qlo  + QKN;
  unsigned short* Klo  = Khi  + QKN;
  unsigned short* Vthi = Klo  + QKN;
  unsigned short* Vtlo = Vthi + QKN;

  proj_kernel<<<dim3(512), 512, 0, stream>>>(
      x, Wq, Wk, Wv, Qhi, Qlo, Khi, Klo, Vthi, Vtlo);
  attn_fused<<<dim3(8, 64), 512, 0, stream>>>(
      Qhi, Qlo, Khi, Klo, Vthi, Vtlo, bw, sw, ss, Onorm);
  outproj_kernel<<<dim3(1024), 512, 0, stream>>>(Onorm, Wo, out);
}

// Round 18
// 32.257 us; speedup vs baseline: 1.5726x; 1.3392x over previous
//
#include <hip/hip_runtime.h>
#include <math.h>

#define NPOS 1024   // H*W
#define DH   32     // dim head
#define NBH  8      // B * HEADS
#define CH   256
#define INNER 128   // HEADS*DIM_HEAD

typedef __attribute__((ext_vector_type(4))) _Float16 half4;
typedef __attribute__((ext_vector_type(4))) float f32x4;

// Canonical CDNA 16x16x16 f16 MFMA.  A: row=l&15, k=4*(l>>4)+j.  B: col=l&15,
// same k ordering.  C/D: col=l&15, row=(l>>4)*4+reg.   (HW-verified by the
// passing attn_fused kernel, R9-R17.)
#define MFMA16(a, b, c) __builtin_amdgcn_mfma_f32_16x16x16f16((a), (b), (c), 0, 0, 0)

// Fragment-tiled f16 layout (NEW in R18): for each 16x16 tile,
//   idx(bh, t, db, lg, lr, j) = ((((bh*64 + t)*2 + db)*4 + lg)*16 + lr)*4 + j
// Q/K: t = n-tile (q or key tile), lr = row within tile, d = db*16 + lg*4 + j.
// V  : t = key tile, lr = d&15, db = d>>4, lg = (key&15)>>2, j = key&3.
// A wave's fragment load (lane l: + lg*64 + lr*4 elems) is one contiguous
// 512B block -> minimal 8-line coalesced VMEM (was a 16-line gather).

union h2u { _Float16 h; unsigned short u; };

__device__ __forceinline__ unsigned short f2h(float f) {
  h2u c; c.h = (_Float16)f; return c.u;
}
__device__ __forceinline__ float h2f(unsigned short u) {
  h2u c; c.u = u; return (float)c.h;
}
__device__ __forceinline__ half4 ldh4(const unsigned short* __restrict__ p) {
  union { half4 v; uint2 u; } r;
  r.u = *(const uint2*)p;
  return r.v;
}
// build half4 fragment pair (hi, lo) from 4 f32 values
__device__ __forceinline__ void split4(const float* v, half4& hi, half4& lo) {
  unsigned short h[4], lw[4];
  #pragma unroll
  for (int j = 0; j < 4; ++j) {
    h[j]  = f2h(v[j]);
    lw[j] = f2h(v[j] - h2f(h[j]));
  }
  union { half4 v4; unsigned int u[2]; } H, L;
  H.u[0] = (unsigned int)h[0]  | ((unsigned int)h[1]  << 16);
  H.u[1] = (unsigned int)h[2]  | ((unsigned int)h[3]  << 16);
  L.u[0] = (unsigned int)lw[0] | ((unsigned int)lw[1] << 16);
  L.u[1] = (unsigned int)lw[2] | ((unsigned int)lw[3] << 16);
  hi = H.v4;  lo = L.v4;
}

// ---------------------------------------------------------------------------
// Kernel A: QKV projection as split-f16 MFMA GEMM + hi/lo encode.
// Same compute as passing R16/R17 version; ONLY the output addresses changed
// to the fragment-tiled layout above.
// ---------------------------------------------------------------------------
__global__ __launch_bounds__(512) void proj_kernel(
    const float* __restrict__ x, const float* __restrict__ Wq,
    const float* __restrict__ Wk, const float* __restrict__ Wv,
    unsigned short* __restrict__ Qhi, unsigned short* __restrict__ Qlo,
    unsigned short* __restrict__ Khi, unsigned short* __restrict__ Klo,
    unsigned short* __restrict__ Vthi, unsigned short* __restrict__ Vtlo)
{
  __shared__ float part[2][3][12][64];   // [job-local][kq-1][acc12][lane] 18KB

  const int tid = threadIdx.x;
  const int l   = tid & 63;
  const int wid = __builtin_amdgcn_readfirstlane(tid >> 6); // 0..7 SGPR
  const int jl  = wid >> 2;        // job within WG (0..1)
  const int kq  = wid & 3;         // K quarter (0..3)

  const int job   = blockIdx.x * 2 + jl;   // 0..1023
  const int b     = job >> 9;
  const int itile = (job >> 6) & 7;
  const int ntile = job & 63;

  const int lr = l & 15;
  const int lg = l >> 4;
  const int i_row = itile * 16 + lr;       // A-operand row (W row)
  const int gn    = ntile * 16 + lr;       // B-operand col (n)

  const float* xb = x + (size_t)b * CH * NPOS;
  const float* wqr = Wq + (size_t)i_row * CH;
  const float* wkr = Wk + (size_t)i_row * CH;
  const float* wvr = Wv + (size_t)i_row * CH;

  f32x4 aq = {0.f,0.f,0.f,0.f}, ak = {0.f,0.f,0.f,0.f}, av = {0.f,0.f,0.f,0.f};

  #pragma unroll
  for (int kk = 0; kk < 4; ++kk) {
    const int cb = kq * 64 + kk * 16 + lg * 4;   // this lane's k base

    // ---- B fragment from x (4 strided loads, split f16) ----
    float xv[4];
    #pragma unroll
    for (int j = 0; j < 4; ++j) xv[j] = xb[(size_t)(cb + j) * NPOS + gn];
    half4 Bhi, Blo;
    split4(xv, Bhi, Blo);

    // ---- A fragments from W (float4 + split), 3 MFMAs each ----
    {
      float4 wv4 = *(const float4*)(wqr + cb);
      float wv[4] = {wv4.x, wv4.y, wv4.z, wv4.w};
      half4 Ahi, Alo;  split4(wv, Ahi, Alo);
      aq = MFMA16(Ahi, Bhi, aq);
      aq = MFMA16(Ahi, Blo, aq);
      aq = MFMA16(Alo, Bhi, aq);
    }
    {
      float4 wv4 = *(const float4*)(wkr + cb);
      float wv[4] = {wv4.x, wv4.y, wv4.z, wv4.w};
      half4 Ahi, Alo;  split4(wv, Ahi, Alo);
      ak = MFMA16(Ahi, Bhi, ak);
      ak = MFMA16(Ahi, Blo, ak);
      ak = MFMA16(Alo, Bhi, ak);
    }
    {
      float4 wv4 = *(const float4*)(wvr + cb);
      float wv[4] = {wv4.x, wv4.y, wv4.z, wv4.w};
      half4 Ahi, Alo;  split4(wv, Ahi, Alo);
      av = MFMA16(Ahi, Bhi, av);
      av = MFMA16(Ahi, Blo, av);
      av = MFMA16(Alo, Bhi, av);
    }
  }

  // ---- K-split combine via LDS ----
  if (kq > 0) {
    #pragma unroll
    for (int r = 0; r < 4; ++r) {
      part[jl][kq - 1][r][l]     = aq[r];
      part[jl][kq - 1][4 + r][l] = ak[r];
      part[jl][kq - 1][8 + r][l] = av[r];
    }
  }
  __syncthreads();
  if (kq > 0) return;

  #pragma unroll
  for (int p = 0; p < 3; ++p)
    #pragma unroll
    for (int r = 0; r < 4; ++r) {
      aq[r] += part[jl][p][r][l];
      ak[r] += part[jl][p][4 + r][l];
      av[r] += part[jl][p][8 + r][l];
    }

  // ---- encode hi/lo f16 and store (fragment-tiled layout) ----
  const float qs = 0.17677669529663687f;  // 1/sqrt(32)
  const int h  = itile >> 1;
  const int bh = b * 4 + h;
  const int db = itile & 1;               // d block (0: d 0-15, 1: d 16-31)

  unsigned short qh[4], ql[4], kh[4], kl[4], vh[4], vl[4];
  #pragma unroll
  for (int r = 0; r < 4; ++r) {
    float q = aq[r] * qs;
    qh[r] = f2h(q);   ql[r] = f2h(q - h2f(qh[r]));
    kh[r] = f2h(ak[r]); kl[r] = f2h(ak[r] - h2f(kh[r]));
    vh[r] = f2h(av[r]); vl[r] = f2h(av[r] - h2f(vh[r]));
  }

  // Q/K: lane (lr,lg) holds d = db*16 + lg*4 + r for row gn -> contiguous 8B
  const size_t qkb = ((((size_t)bh * 64 + ntile) * 2 + db) * 4 + lg) * 64
                   + (size_t)lr * 4;
  *(uint2*)(Qhi + qkb) = make_uint2((unsigned)qh[0] | ((unsigned)qh[1] << 16),
                                    (unsigned)qh[2] | ((unsigned)qh[3] << 16));
  *(uint2*)(Qlo + qkb) = make_uint2((unsigned)ql[0] | ((unsigned)ql[1] << 16),
                                    (unsigned)ql[2] | ((unsigned)ql[3] << 16));
  *(uint2*)(Khi + qkb) = make_uint2((unsigned)kh[0] | ((unsigned)kh[1] << 16),
                                    (unsigned)kh[2] | ((unsigned)kh[3] << 16));
  *(uint2*)(Klo + qkb) = make_uint2((unsigned)kl[0] | ((unsigned)kl[1] << 16),
                                    (unsigned)kl[2] | ((unsigned)kl[3] << 16));

  // V: transposed fragment (lr_tgt = d&15 = lg*4+r, lg_tgt = lr>>2, j = lr&3)
  #pragma unroll
  for (int r = 0; r < 4; ++r) {
    const size_t vb = ((((size_t)bh * 64 + ntile) * 2 + db) * 4 + (lr >> 2)) * 64
                    + (size_t)(lg * 4 + r) * 4 + (lr & 3);
    Vthi[vb] = vh[r];
    Vtlo[vb] = vl[r];
  }
}

// ---------------------------------------------------------------------------
// Kernel B: fully fused attention.  Same compute as passing R9-R17 version;
// ONLY the fragment load addresses changed to the tile-linear layout
// (each ldh4 now reads from a contiguous 512B block).
// ---------------------------------------------------------------------------
__global__ __launch_bounds__(512) void attn_fused(
    const unsigned short* __restrict__ Qhi, const unsigned short* __restrict__ Qlo,
    const unsigned short* __restrict__ Khi, const unsigned short* __restrict__ Klo,
    const unsigned short* __restrict__ Vthi, const unsigned short* __restrict__ Vtlo,
    const float* __restrict__ bwp, const float* __restrict__ swp,
    const float* __restrict__ ssp, float* __restrict__ Onorm)
{
  __shared__ float DlO[8][32][17];
  __shared__ float DlS[8][4][17];

  const int tid = threadIdx.x;
  const int l   = tid & 63;
  const int w   = tid >> 6;        // 0..7
  const int lr  = l & 15;
  const int lg  = l >> 4;          // 0..3
  const int bh  = blockIdx.x;      // 0..7 (== XCD)
  const int q0  = blockIdx.y * 16;

  const int fo  = lg * 64 + lr * 4;   // fragment offset within a (t,db) block

  // ---- uniform KAN constants ----
  const float sc = ssp[0];
  const float bw = bwp[0];
  float C[8];
  #pragma unroll
  for (int j = 0; j < 8; ++j) C[j] = swp[j] * sc;
  float maxc = 0.f;
  #pragma unroll
  for (int j = 0; j < 8; ++j) maxc = fmaxf(maxc, fabsf(C[j]));
  const float Bnd = fabsf(bw) * 6.0f + maxc;    // >= max_x kan(x)

  float A0[5], A1[5], A2[5], A3[5];             // per-cell cubic; -Bnd in A0
  #pragma unroll
  for (int c = 0; c < 5; ++c) {
    A0[c] = (C[c] + 4.f * C[c+1] + C[c+2]) * (1.f / 6.f) - Bnd;
    A1[c] = (-3.f * C[c] + 3.f * C[c+2]) * (1.f / 6.f);
    A2[c] = (3.f * C[c] - 6.f * C[c+1] + 3.f * C[c+2]) * (1.f / 6.f);
    A3[c] = (-C[c] + 3.f * C[c+1] - 3.f * C[c+2] + C[c+3]) * (1.f / 6.f);
  }

  // ---- Q fragments (B-operand, persistent): tile t = q0>>4 ----
  const size_t qtb = ((size_t)bh * 64 + (q0 >> 4)) * 512;
  const half4 Bq_h0 = ldh4(Qhi + qtb + fo);
  const half4 Bq_h1 = ldh4(Qhi + qtb + 256 + fo);
  const half4 Bq_l0 = ldh4(Qlo + qtb + fo);
  const half4 Bq_l1 = ldh4(Qlo + qtb + 256 + fo);

  f32x4 accO0 = {0.f, 0.f, 0.f, 0.f};   // d 0..15
  f32x4 accO1 = {0.f, 0.f, 0.f, 0.f};   // d 16..31
  float ssum = 0.f;

  #pragma unroll 2
  for (int t = 0; t < 8; ++t) {
    const int kt  = w * 8 + t;              // key tile index
    const size_t ktb = ((size_t)bh * 64 + kt) * 512;

    // ---- QK: A = K fragment (coalesced 512B block reads) ----
    const half4 Ak_h0 = ldh4(Khi + ktb + fo);
    const half4 Ak_h1 = ldh4(Khi + ktb + 256 + fo);
    const half4 Ak_l0 = ldh4(Klo + ktb + fo);
    const half4 Ak_l1 = ldh4(Klo + ktb + 256 + fo);

    f32x4 acc = {0.f, 0.f, 0.f, 0.f};
    acc = MFMA16(Ak_h0, Bq_h0, acc);
    acc = MFMA16(Ak_h1, Bq_h1, acc);
    acc = MFMA16(Ak_h0, Bq_l0, acc);
    acc = MFMA16(Ak_h1, Bq_l1, acc);
    acc = MFMA16(Ak_l0, Bq_h0, acc);
    acc = MFMA16(Ak_l1, Bq_h1, acc);
    // acc[r] = S[q=q0+lr][k = kt*16 + 4*lg + r]

    // ---- KAN + exp(kan - Bnd) on 4 values; keep f16-consistent p ----
    unsigned short ph[4];
    #pragma unroll
    for (int r = 0; r < 4; ++r) {
      float s = acc[r];
      s = fminf(fmaxf(s, -6.0f), 6.0f);
      float e   = __expf(-s);
      float sil = s * __builtin_amdgcn_rcpf(1.0f + e);
      float tt  = fmaf(s, (1.0f / 2.4f), 2.5f);   // (s+6)/2.4 in [0,5]
      float cf  = fminf(floorf(tt), 4.0f);
      float u   = tt - cf;
      float a0 = A0[0], a1 = A1[0], a2 = A2[0], a3 = A3[0];
      a0 = cf >= 0.5f ? A0[1] : a0;  a1 = cf >= 0.5f ? A1[1] : a1;
      a2 = cf >= 0.5f ? A2[1] : a2;  a3 = cf >= 0.5f ? A3[1] : a3;
      a0 = cf >= 1.5f ? A0[2] : a0;  a1 = cf >= 1.5f ? A1[2] : a1;
      a2 = cf >= 1.5f ? A2[2] : a2;  a3 = cf >= 1.5f ? A3[2] : a3;
      a0 = cf >= 2.5f ? A0[3] : a0;  a1 = cf >= 2.5f ? A1[3] : a1;
      a2 = cf >= 2.5f ? A2[3] : a2;  a3 = cf >= 2.5f ? A3[3] : a3;
      a0 = cf >= 3.5f ? A0[4] : a0;  a1 = cf >= 3.5f ? A1[4] : a1;
      a2 = cf >= 3.5f ? A2[4] : a2;  a3 = cf >= 3.5f ? A3[4] : a3;
      float spl = fmaf(fmaf(fmaf(a3, u, a2), u, a1), u, a0);  // includes -Bnd
      float kan = fmaf(bw, sil, spl);
      unsigned short pu = f2h(__expf(kan));
      ph[r] = pu;
      ssum += h2f(pu);          // SAME rounded value PV consumes
    }
    union { half4 v; unsigned int u[2]; } Pb;
    Pb.u[0] = (unsigned int)ph[0] | ((unsigned int)ph[1] << 16);
    Pb.u[1] = (unsigned int)ph[2] | ((unsigned int)ph[3] << 16);
    // Pb is the B-operand fragment: col q = lr, k-elem j = key kt*16+4*lg+j

    // ---- PV: O^T += V^T · P^T  (A = V^T fragments, coalesced reads) ----
    const half4 Av_h0 = ldh4(Vthi + ktb + fo);         // d = lr
    const half4 Av_l0 = ldh4(Vtlo + ktb + fo);
    const half4 Av_h1 = ldh4(Vthi + ktb + 256 + fo);   // d = 16 + lr
    const half4 Av_l1 = ldh4(Vtlo + ktb + 256 + fo);
    accO0 = MFMA16(Av_h0, Pb.v, accO0);
    accO0 = MFMA16(Av_l0, Pb.v, accO0);
    accO1 = MFMA16(Av_h1, Pb.v, accO1);
    accO1 = MFMA16(Av_l1, Pb.v, accO1);
  }

  // ---- 8-way combine ----
  #pragma unroll
  for (int r = 0; r < 4; ++r) {
    DlO[w][4 * lg + r][lr]      = accO0[r];   // accO[r]: d = 4*lg+r, q = lr
    DlO[w][16 + 4 * lg + r][lr] = accO1[r];
  }
  DlS[w][lg][lr] = ssum;
  __syncthreads();

  {
    const int q = tid & 15;
    const int d = tid >> 4;     // 0..31 (512 threads)
    float o = 0.f, sden = 0.f;
    #pragma unroll
    for (int ww = 0; ww < 8; ++ww) {
      o += DlO[ww][d][q];
      #pragma unroll
      for (int g = 0; g < 4; ++g) sden += DlS[ww][g][q];
    }
    Onorm[((size_t)bh * DH + d) * NPOS + q0 + q] = o / sden;
  }
}

// ---------------------------------------------------------------------------
// Kernel C: output projection as split-f16 MFMA GEMM (UNCHANGED from R17).
// ---------------------------------------------------------------------------
__global__ __launch_bounds__(512) void outproj_kernel(
    const float* __restrict__ Onorm, const float* __restrict__ Wo,
    float* __restrict__ out)
{
  __shared__ float part[2][3][4][64];   // [job-local][kq-1][acc][lane], 6 KB

  const int tid = threadIdx.x;
  const int l   = tid & 63;
  const int wid = __builtin_amdgcn_readfirstlane(tid >> 6); // 0..7 SGPR
  const int jl  = wid >> 2;        // job within WG (0..1)
  const int kq  = wid & 3;         // K quarter (0..3), 32 i each

  const int job   = blockIdx.x * 2 + jl;   // 0..2047
  const int b     = job >> 10;
  const int ctile = (job >> 6) & 15;
  const int ntile = job & 63;

  const int lr = l & 15;
  const int lg = l >> 4;
  const int c_row = ctile * 16 + lr;       // A-operand row (Wo row)
  const int gn    = ntile * 16 + lr;       // B-operand col (n)

  const float* ob = Onorm + (size_t)b * INNER * NPOS;
  const float* wr = Wo + (size_t)c_row * INNER;

  f32x4 acc = {0.f, 0.f, 0.f, 0.f};

  #pragma unroll
  for (int kk = 0; kk < 2; ++kk) {
    const int ib = kq * 32 + kk * 16 + lg * 4;   // this lane's i base

    float xv[4];
    #pragma unroll
    for (int j = 0; j < 4; ++j) xv[j] = ob[(size_t)(ib + j) * NPOS + gn];
    half4 Bhi, Blo;
    split4(xv, Bhi, Blo);

    float4 wv4 = *(const float4*)(wr + ib);
    float wv[4] = {wv4.x, wv4.y, wv4.z, wv4.w};
    half4 Ahi, Alo;
    split4(wv, Ahi, Alo);

    acc = MFMA16(Ahi, Bhi, acc);
    acc = MFMA16(Ahi, Blo, acc);
    acc = MFMA16(Alo, Bhi, acc);
  }

  if (kq > 0) {
    #pragma unroll
    for (int r = 0; r < 4; ++r) part[jl][kq - 1][r][l] = acc[r];
  }
  __syncthreads();
  if (kq > 0) return;

  #pragma unroll
  for (int p = 0; p < 3; ++p)
    #pragma unroll
    for (int r = 0; r < 4; ++r) acc[r] += part[jl][p][r][l];

  #pragma unroll
  for (int r = 0; r < 4; ++r) {
    const int c = ctile * 16 + lg * 4 + r;
    out[((size_t)(b * CH + c)) * NPOS + gn] = acc[r];
  }
}

// ---------------------------------------------------------------------------
extern "C" void kernel_launch(void* const* d_in, const int* in_sizes, int n_in,
                              void* d_out, int out_size, void* d_ws, size_t ws_size,
                              hipStream_t stream)
{
  const float* x  = (const float*)d_in[0];
  const float* Wq = (const float*)d_in[1];
  const float* Wk = (const float*)d_in[2];
  const float* Wv = (const float*)d_in[3];
  const float* Wo = (const float*)d_in[4];
  const float* bw = (const float*)d_in[5];
  const float* sw = (const float*)d_in[6];
  const float* ss = (const float*)d_in[7];
  float* out = (float*)d_out;

  // workspace: Onorm (f32, 1MB) | 6x f16 QKV (512KB each, fragment-tiled)
  float* Onorm = (float*)d_ws;
  unsigned short* base = (unsigned short*)(Onorm + (size_t)NBH * DH * NPOS);
  const size_t QKN = (size_t)NBH * NPOS * DH;   // 262144 elements
  unsigned short* Qhi  = base;
  unsigned short* Qlo  = Qhi  + QKN;
  unsigned short* Khi  = Qlo  + QKN;
  unsigned short* Klo  = Khi  + QKN;
  unsigned short* Vthi = Klo  + QKN;
  unsigned short* Vtlo = Vthi + QKN;

  proj_kernel<<<dim3(512), 512, 0, stream>>>(
      x, Wq, Wk, Wv, Qhi, Qlo, Khi, Klo, Vthi, Vtlo);
  attn_fused<<<dim3(8, 64), 512, 0, stream>>>(
      Qhi, Qlo, Khi, Klo, Vthi, Vtlo, bw, sw, ss, Onorm);
  outproj_kernel<<<dim3(1024), 512, 0, stream>>>(Onorm, Wo, out);
}

// Round 19
// 30.337 us; speedup vs baseline: 1.6721x; 1.0633x over previous
//
#include <hip/hip_runtime.h>
#include <math.h>

#define NPOS 1024   // H*W
#define DH   32     // dim head
#define NBH  8      // B * HEADS
#define CH   256
#define INNER 128   // HEADS*DIM_HEAD

typedef __attribute__((ext_vector_type(4))) _Float16 half4;
typedef __attribute__((ext_vector_type(4))) float f32x4;

// Canonical CDNA 16x16x16 f16 MFMA.  A: row=l&15, k=4*(l>>4)+j.  B: col=l&15,
// same k ordering.  C/D: col=l&15, row=(l>>4)*4+reg.   (HW-verified by the
// passing attn_fused kernel, R9-R18.)
#define MFMA16(a, b, c) __builtin_amdgcn_mfma_f32_16x16x16f16((a), (b), (c), 0, 0, 0)

// Fragment-tiled f16 layout (R18, passing): for each 16x16 tile,
//   idx(bh, t, db, lg, lr, j) = ((((bh*64 + t)*2 + db)*4 + lg)*16 + lr)*4 + j
// Q/K: t = n-tile, lr = row within tile, d = db*16 + lg*4 + j.
// V  : t = key tile, lr = d&15, db = d>>4, lg = (key&15)>>2, j = key&3.

union h2u { _Float16 h; unsigned short u; };

__device__ __forceinline__ unsigned short f2h(float f) {
  h2u c; c.h = (_Float16)f; return c.u;
}
__device__ __forceinline__ float h2f(unsigned short u) {
  h2u c; c.u = u; return (float)c.h;
}
__device__ __forceinline__ half4 ldh4(const unsigned short* __restrict__ p) {
  union { half4 v; uint2 u; } r;
  r.u = *(const uint2*)p;
  return r.v;
}
// build half4 fragment pair (hi, lo) from 4 f32 values
__device__ __forceinline__ void split4(const float* v, half4& hi, half4& lo) {
  unsigned short h[4], lw[4];
  #pragma unroll
  for (int j = 0; j < 4; ++j) {
    h[j]  = f2h(v[j]);
    lw[j] = f2h(v[j] - h2f(h[j]));
  }
  union { half4 v4; unsigned int u[2]; } H, L;
  H.u[0] = (unsigned int)h[0]  | ((unsigned int)h[1]  << 16);
  H.u[1] = (unsigned int)h[2]  | ((unsigned int)h[3]  << 16);
  L.u[0] = (unsigned int)lw[0] | ((unsigned int)lw[1] << 16);
  L.u[1] = (unsigned int)lw[2] | ((unsigned int)lw[3] << 16);
  hi = H.v4;  lo = L.v4;
}

// ---------------------------------------------------------------------------
// Kernel A: QKV projection as split-f16 MFMA GEMM + hi/lo encode.
// (UNCHANGED from passing R18 version.)
// ---------------------------------------------------------------------------
__global__ __launch_bounds__(512) void proj_kernel(
    const float* __restrict__ x, const float* __restrict__ Wq,
    const float* __restrict__ Wk, const float* __restrict__ Wv,
    unsigned short* __restrict__ Qhi, unsigned short* __restrict__ Qlo,
    unsigned short* __restrict__ Khi, unsigned short* __restrict__ Klo,
    unsigned short* __restrict__ Vthi, unsigned short* __restrict__ Vtlo)
{
  __shared__ float part[2][3][12][64];   // [job-local][kq-1][acc12][lane] 18KB

  const int tid = threadIdx.x;
  const int l   = tid & 63;
  const int wid = __builtin_amdgcn_readfirstlane(tid >> 6); // 0..7 SGPR
  const int jl  = wid >> 2;        // job within WG (0..1)
  const int kq  = wid & 3;         // K quarter (0..3)

  const int job   = blockIdx.x * 2 + jl;   // 0..1023
  const int b     = job >> 9;
  const int itile = (job >> 6) & 7;
  const int ntile = job & 63;

  const int lr = l & 15;
  const int lg = l >> 4;
  const int i_row = itile * 16 + lr;       // A-operand row (W row)
  const int gn    = ntile * 16 + lr;       // B-operand col (n)

  const float* xb = x + (size_t)b * CH * NPOS;
  const float* wqr = Wq + (size_t)i_row * CH;
  const float* wkr = Wk + (size_t)i_row * CH;
  const float* wvr = Wv + (size_t)i_row * CH;

  f32x4 aq = {0.f,0.f,0.f,0.f}, ak = {0.f,0.f,0.f,0.f}, av = {0.f,0.f,0.f,0.f};

  #pragma unroll
  for (int kk = 0; kk < 4; ++kk) {
    const int cb = kq * 64 + kk * 16 + lg * 4;   // this lane's k base

    // ---- B fragment from x (4 strided loads, split f16) ----
    float xv[4];
    #pragma unroll
    for (int j = 0; j < 4; ++j) xv[j] = xb[(size_t)(cb + j) * NPOS + gn];
    half4 Bhi, Blo;
    split4(xv, Bhi, Blo);

    // ---- A fragments from W (float4 + split), 3 MFMAs each ----
    {
      float4 wv4 = *(const float4*)(wqr + cb);
      float wv[4] = {wv4.x, wv4.y, wv4.z, wv4.w};
      half4 Ahi, Alo;  split4(wv, Ahi, Alo);
      aq = MFMA16(Ahi, Bhi, aq);
      aq = MFMA16(Ahi, Blo, aq);
      aq = MFMA16(Alo, Bhi, aq);
    }
    {
      float4 wv4 = *(const float4*)(wkr + cb);
      float wv[4] = {wv4.x, wv4.y, wv4.z, wv4.w};
      half4 Ahi, Alo;  split4(wv, Ahi, Alo);
      ak = MFMA16(Ahi, Bhi, ak);
      ak = MFMA16(Ahi, Blo, ak);
      ak = MFMA16(Alo, Bhi, ak);
    }
    {
      float4 wv4 = *(const float4*)(wvr + cb);
      float wv[4] = {wv4.x, wv4.y, wv4.z, wv4.w};
      half4 Ahi, Alo;  split4(wv, Ahi, Alo);
      av = MFMA16(Ahi, Bhi, av);
      av = MFMA16(Ahi, Blo, av);
      av = MFMA16(Alo, Bhi, av);
    }
  }

  // ---- K-split combine via LDS ----
  if (kq > 0) {
    #pragma unroll
    for (int r = 0; r < 4; ++r) {
      part[jl][kq - 1][r][l]     = aq[r];
      part[jl][kq - 1][4 + r][l] = ak[r];
      part[jl][kq - 1][8 + r][l] = av[r];
    }
  }
  __syncthreads();
  if (kq > 0) return;

  #pragma unroll
  for (int p = 0; p < 3; ++p)
    #pragma unroll
    for (int r = 0; r < 4; ++r) {
      aq[r] += part[jl][p][r][l];
      ak[r] += part[jl][p][4 + r][l];
      av[r] += part[jl][p][8 + r][l];
    }

  // ---- encode hi/lo f16 and store (fragment-tiled layout) ----
  const float qs = 0.17677669529663687f;  // 1/sqrt(32)
  const int h  = itile >> 1;
  const int bh = b * 4 + h;
  const int db = itile & 1;               // d block (0: d 0-15, 1: d 16-31)

  unsigned short qh[4], ql[4], kh[4], kl[4], vh[4], vl[4];
  #pragma unroll
  for (int r = 0; r < 4; ++r) {
    float q = aq[r] * qs;
    qh[r] = f2h(q);   ql[r] = f2h(q - h2f(qh[r]));
    kh[r] = f2h(ak[r]); kl[r] = f2h(ak[r] - h2f(kh[r]));
    vh[r] = f2h(av[r]); vl[r] = f2h(av[r] - h2f(vh[r]));
  }

  // Q/K: lane (lr,lg) holds d = db*16 + lg*4 + r for row gn -> contiguous 8B
  const size_t qkb = ((((size_t)bh * 64 + ntile) * 2 + db) * 4 + lg) * 64
                   + (size_t)lr * 4;
  *(uint2*)(Qhi + qkb) = make_uint2((unsigned)qh[0] | ((unsigned)qh[1] << 16),
                                    (unsigned)qh[2] | ((unsigned)qh[3] << 16));
  *(uint2*)(Qlo + qkb) = make_uint2((unsigned)ql[0] | ((unsigned)ql[1] << 16),
                                    (unsigned)ql[2] | ((unsigned)ql[3] << 16));
  *(uint2*)(Khi + qkb) = make_uint2((unsigned)kh[0] | ((unsigned)kh[1] << 16),
                                    (unsigned)kh[2] | ((unsigned)kh[3] << 16));
  *(uint2*)(Klo + qkb) = make_uint2((unsigned)kl[0] | ((unsigned)kl[1] << 16),
                                    (unsigned)kl[2] | ((unsigned)kl[3] << 16));

  // V: transposed fragment (lr_tgt = d&15 = lg*4+r, lg_tgt = lr>>2, j = lr&3)
  #pragma unroll
  for (int r = 0; r < 4; ++r) {
    const size_t vb = ((((size_t)bh * 64 + ntile) * 2 + db) * 4 + (lr >> 2)) * 64
                    + (size_t)(lg * 4 + r) * 4 + (lr & 3);
    Vthi[vb] = vh[r];
    Vtlo[vb] = vl[r];
  }
}

// ---------------------------------------------------------------------------
// Kernel B: fully fused attention.  Same as passing R18 version EXCEPT the
// per-cell cubic coefficients are fetched from a 5x4 LDS table (one
// conflict-free ds_read_b128) instead of a 25-op cndmask select chain.
// Table entries are computed with the SAME formulas -> bit-identical output.
// ---------------------------------------------------------------------------
__global__ __launch_bounds__(512) void attn_fused(
    const unsigned short* __restrict__ Qhi, const unsigned short* __restrict__ Qlo,
    const unsigned short* __restrict__ Khi, const unsigned short* __restrict__ Klo,
    const unsigned short* __restrict__ Vthi, const unsigned short* __restrict__ Vtlo,
    const float* __restrict__ bwp, const float* __restrict__ swp,
    const float* __restrict__ ssp, float* __restrict__ Onorm)
{
  __shared__ float DlO[8][32][17];
  __shared__ float DlS[8][4][17];
  __shared__ float tabL[5][4];     // per-cell cubic coeffs, -Bnd folded in a0

  const int tid = threadIdx.x;
  const int l   = tid & 63;
  const int w   = tid >> 6;        // 0..7
  const int lr  = l & 15;
  const int lg  = l >> 4;          // 0..3
  const int bh  = blockIdx.x;      // 0..7 (== XCD)
  const int q0  = blockIdx.y * 16;

  const int fo  = lg * 64 + lr * 4;   // fragment offset within a (t,db) block

  // ---- uniform KAN constants ----
  const float sc = ssp[0];
  const float bw = bwp[0];

  // build coefficient table (20 threads; same formulas as the old per-thread
  // select-chain version -> identical IEEE values)
  if (tid < 20) {
    const int cell = tid >> 2, p = tid & 3;
    float C[8];
    #pragma unroll
    for (int j = 0; j < 8; ++j) C[j] = swp[j] * sc;
    float maxc = 0.f;
    #pragma unroll
    for (int j = 0; j < 8; ++j) maxc = fmaxf(maxc, fabsf(C[j]));
    const float Bnd = fabsf(bw) * 6.0f + maxc;
    float a;
    if      (p == 0) a = (C[cell] + 4.f * C[cell+1] + C[cell+2]) * (1.f / 6.f) - Bnd;
    else if (p == 1) a = (-3.f * C[cell] + 3.f * C[cell+2]) * (1.f / 6.f);
    else if (p == 2) a = (3.f * C[cell] - 6.f * C[cell+1] + 3.f * C[cell+2]) * (1.f / 6.f);
    else             a = (-C[cell] + 3.f * C[cell+1] - 3.f * C[cell+2] + C[cell+3]) * (1.f / 6.f);
    tabL[cell][p] = a;
  }
  __syncthreads();

  // ---- Q fragments (B-operand, persistent): tile t = q0>>4 ----
  const size_t qtb = ((size_t)bh * 64 + (q0 >> 4)) * 512;
  const half4 Bq_h0 = ldh4(Qhi + qtb + fo);
  const half4 Bq_h1 = ldh4(Qhi + qtb + 256 + fo);
  const half4 Bq_l0 = ldh4(Qlo + qtb + fo);
  const half4 Bq_l1 = ldh4(Qlo + qtb + 256 + fo);

  f32x4 accO0 = {0.f, 0.f, 0.f, 0.f};   // d 0..15
  f32x4 accO1 = {0.f, 0.f, 0.f, 0.f};   // d 16..31
  float ssum = 0.f;

  #pragma unroll 2
  for (int t = 0; t < 8; ++t) {
    const int kt  = w * 8 + t;              // key tile index
    const size_t ktb = ((size_t)bh * 64 + kt) * 512;

    // ---- QK: A = K fragment (coalesced 512B block reads) ----
    const half4 Ak_h0 = ldh4(Khi + ktb + fo);
    const half4 Ak_h1 = ldh4(Khi + ktb + 256 + fo);
    const half4 Ak_l0 = ldh4(Klo + ktb + fo);
    const half4 Ak_l1 = ldh4(Klo + ktb + 256 + fo);

    f32x4 acc = {0.f, 0.f, 0.f, 0.f};
    acc = MFMA16(Ak_h0, Bq_h0, acc);
    acc = MFMA16(Ak_h1, Bq_h1, acc);
    acc = MFMA16(Ak_h0, Bq_l0, acc);
    acc = MFMA16(Ak_h1, Bq_l1, acc);
    acc = MFMA16(Ak_l0, Bq_h0, acc);
    acc = MFMA16(Ak_l1, Bq_h1, acc);
    // acc[r] = S[q=q0+lr][k = kt*16 + 4*lg + r]

    // ---- KAN + exp(kan - Bnd); coefficients via LDS gather ----
    unsigned short ph[4];
    #pragma unroll
    for (int r = 0; r < 4; ++r) {
      float s = acc[r];
      s = fminf(fmaxf(s, -6.0f), 6.0f);
      float e   = __expf(-s);
      float sil = s * __builtin_amdgcn_rcpf(1.0f + e);
      float tt  = fmaf(s, (1.0f / 2.4f), 2.5f);   // (s+6)/2.4 in [0,5]
      float cf  = fminf(floorf(tt), 4.0f);
      float u   = tt - cf;
      const float4 cv = *(const float4*)tabL[(int)cf];   // ds_read_b128
      float spl = fmaf(fmaf(fmaf(cv.w, u, cv.z), u, cv.y), u, cv.x); // incl -Bnd
      float kan = fmaf(bw, sil, spl);
      unsigned short pu = f2h(__expf(kan));
      ph[r] = pu;
      ssum += h2f(pu);          // SAME rounded value PV consumes
    }
    union { half4 v; unsigned int u[2]; } Pb;
    Pb.u[0] = (unsigned int)ph[0] | ((unsigned int)ph[1] << 16);
    Pb.u[1] = (unsigned int)ph[2] | ((unsigned int)ph[3] << 16);
    // Pb is the B-operand fragment: col q = lr, k-elem j = key kt*16+4*lg+j

    // ---- PV: O^T += V^T · P^T  (A = V^T fragments, coalesced reads) ----
    const half4 Av_h0 = ldh4(Vthi + ktb + fo);         // d = lr
    const half4 Av_l0 = ldh4(Vtlo + ktb + fo);
    const half4 Av_h1 = ldh4(Vthi + ktb + 256 + fo);   // d = 16 + lr
    const half4 Av_l1 = ldh4(Vtlo + ktb + 256 + fo);
    accO0 = MFMA16(Av_h0, Pb.v, accO0);
    accO0 = MFMA16(Av_l0, Pb.v, accO0);
    accO1 = MFMA16(Av_h1, Pb.v, accO1);
    accO1 = MFMA16(Av_l1, Pb.v, accO1);
  }

  // ---- 8-way combine ----
  #pragma unroll
  for (int r = 0; r < 4; ++r) {
    DlO[w][4 * lg + r][lr]      = accO0[r];   // accO[r]: d = 4*lg+r, q = lr
    DlO[w][16 + 4 * lg + r][lr] = accO1[r];
  }
  DlS[w][lg][lr] = ssum;
  __syncthreads();

  {
    const int q = tid & 15;
    const int d = tid >> 4;     // 0..31 (512 threads)
    float o = 0.f, sden = 0.f;
    #pragma unroll
    for (int ww = 0; ww < 8; ++ww) {
      o += DlO[ww][d][q];
      #pragma unroll
      for (int g = 0; g < 4; ++g) sden += DlS[ww][g][q];
    }
    Onorm[((size_t)bh * DH + d) * NPOS + q0 + q] = o / sden;
  }
}

// ---------------------------------------------------------------------------
// Kernel C: output projection as split-f16 MFMA GEMM (UNCHANGED from R17/R18).
// ---------------------------------------------------------------------------
__global__ __launch_bounds__(512) void outproj_kernel(
    const float* __restrict__ Onorm, const float* __restrict__ Wo,
    float* __restrict__ out)
{
  __shared__ float part[2][3][4][64];   // [job-local][kq-1][acc][lane], 6 KB

  const int tid = threadIdx.x;
  const int l   = tid & 63;
  const int wid = __builtin_amdgcn_readfirstlane(tid >> 6); // 0..7 SGPR
  const int jl  = wid >> 2;        // job within WG (0..1)
  const int kq  = wid & 3;         // K quarter (0..3), 32 i each

  const int job   = blockIdx.x * 2 + jl;   // 0..2047
  const int b     = job >> 10;
  const int ctile = (job >> 6) & 15;
  const int ntile = job & 63;

  const int lr = l & 15;
  const int lg = l >> 4;
  const int c_row = ctile * 16 + lr;       // A-operand row (Wo row)
  const int gn    = ntile * 16 + lr;       // B-operand col (n)

  const float* ob = Onorm + (size_t)b * INNER * NPOS;
  const float* wr = Wo + (size_t)c_row * INNER;

  f32x4 acc = {0.f, 0.f, 0.f, 0.f};

  #pragma unroll
  for (int kk = 0; kk < 2; ++kk) {
    const int ib = kq * 32 + kk * 16 + lg * 4;   // this lane's i base

    float xv[4];
    #pragma unroll
    for (int j = 0; j < 4; ++j) xv[j] = ob[(size_t)(ib + j) * NPOS + gn];
    half4 Bhi, Blo;
    split4(xv, Bhi, Blo);

    float4 wv4 = *(const float4*)(wr + ib);
    float wv[4] = {wv4.x, wv4.y, wv4.z, wv4.w};
    half4 Ahi, Alo;
    split4(wv, Ahi, Alo);

    acc = MFMA16(Ahi, Bhi, acc);
    acc = MFMA16(Ahi, Blo, acc);
    acc = MFMA16(Alo, Bhi, acc);
  }

  if (kq > 0) {
    #pragma unroll
    for (int r = 0; r < 4; ++r) part[jl][kq - 1][r][l] = acc[r];
  }
  __syncthreads();
  if (kq > 0) return;

  #pragma unroll
  for (int p = 0; p < 3; ++p)
    #pragma unroll
    for (int r = 0; r < 4; ++r) acc[r] += part[jl][p][r][l];

  #pragma unroll
  for (int r = 0; r < 4; ++r) {
    const int c = ctile * 16 + lg * 4 + r;
    out[((size_t)(b * CH + c)) * NPOS + gn] = acc[r];
  }
}

// ---------------------------------------------------------------------------
extern "C" void kernel_launch(void* const* d_in, const int* in_sizes, int n_in,
                              void* d_out, int out_size, void* d_ws, size_t ws_size,
                              hipStream_t stream)
{
  const float* x  = (const float*)d_in[0];
  const float* Wq = (const float*)d_in[1];
  const float* Wk = (const float*)d_in[2];
  const float* Wv = (const float*)d_in[3];
  const float* Wo = (const float*)d_in[4];
  const float* bw = (const float*)d_in[5];
  const float* sw = (const float*)d_in[6];
  const float* ss = (const float*)d_in[7];
  float* out = (float*)d_out;

  // workspace: Onorm (f32, 1MB) | 6x f16 QKV (512KB each, fragment-tiled)
  float* Onorm = (float*)d_ws;
  unsigned short* base = (unsigned short*)(Onorm + (size_t)NBH * DH * NPOS);
  const size_t QKN = (size_t)NBH * NPOS * DH;   // 262144 elements
  unsigned short* Qhi  = base;
  unsigned short* Qlo  = Qhi  + QKN;
  unsigned short* Khi  = Qlo  + QKN;
  unsigned short* Klo  = Khi  + QKN;
  unsigned short* Vthi = Klo  + QKN;
  unsigned short* Vtlo = Vthi + QKN;

  proj_kernel<<<dim3(512), 512, 0, stream>>>(
      x, Wq, Wk, Wv, Qhi, Qlo, Khi, Klo, Vthi, Vtlo);
  attn_fused<<<dim3(8, 64), 512, 0, stream>>>(
      Qhi, Qlo, Khi, Klo, Vthi, Vtlo, bw, sw, ss, Onorm);
  outproj_kernel<<<dim3(1024), 512, 0, stream>>>(Onorm, Wo, out);
}